// Round 4
// baseline (507.387 us; speedup 1.0000x reference)
//
#include <hip/hip_runtime.h>
#include <hip/hip_bf16.h>
#include <math.h>

#define NN 4096
#define DD 256

typedef __bf16 bf16x8 __attribute__((ext_vector_type(8)));
typedef short  short8 __attribute__((ext_vector_type(8)));
typedef float  f32x4  __attribute__((ext_vector_type(4)));
typedef float  f32x16 __attribute__((ext_vector_type(16)));

typedef __attribute__((address_space(1))) const void gv_t;
typedef __attribute__((address_space(3))) void lv_t;
#define GLD16(gp, lp) __builtin_amdgcn_global_load_lds((gv_t*)(gp), (lv_t*)(lp), 16, 0, 0)

#define MFMA16(a, b, c) __builtin_amdgcn_mfma_f32_16x16x32_bf16((a), (b), (c), 0, 0, 0)
#define MFMA32(a, b, c) __builtin_amdgcn_mfma_f32_32x32x16_bf16((a), (b), (c), 0, 0, 0)

__device__ inline bf16x8 brelu(bf16x8 a) {
    short8 s = __builtin_bit_cast(short8, a);
    s = s & ~(s >> 15);            // negative (sign bit set) -> 0, else keep
    return __builtin_bit_cast(bf16x8, s);
}

__device__ inline float wave_red(float v) {
#pragma unroll
    for (int o = 32; o > 0; o >>= 1) v += __shfl_down(v, o, 64);
    return v;
}

__device__ inline unsigned short bfbits(float f) {
    return __builtin_bit_cast(unsigned short, (__bf16)f);
}

__device__ inline void syncb() {
    asm volatile("s_waitcnt lgkmcnt(0)" ::: "memory");
    __builtin_amdgcn_s_barrier();
}

// store/load one 32x32 f32 fragment (16 regs/lane) to a 4KB LDS slot, bank-balanced.
__device__ inline void store16(float* base, const f32x16& v, int lane) {
#pragma unroll
    for (int r4 = 0; r4 < 4; ++r4) {
        f32x4 c = {v[4 * r4], v[4 * r4 + 1], v[4 * r4 + 2], v[4 * r4 + 3]};
        ((f32x4*)base)[r4 * 64 + lane] = c;
    }
}
__device__ inline void add16(f32x16& v, const float* base, int lane) {
#pragma unroll
    for (int r4 = 0; r4 < 4; ++r4) {
        f32x4 c = ((const f32x4*)base)[r4 * 64 + lane];
        v[4 * r4] += c[0]; v[4 * r4 + 1] += c[1]; v[4 * r4 + 2] += c[2]; v[4 * r4 + 3] += c[3];
    }
}

// cross-wave K-split reduction: wave W ends owning quadrant (mi=W>>1, ni=W&1).
template <int W>
__device__ inline void red_owner(f32x16 (&aR)[2][2], f32x16 (&aL)[2][2],
                                 float* scr, int lane, f32x16& oR, f32x16& oL) {
    constexpr int o1 = W ^ 1, o2 = W ^ 2, o3 = W ^ 3;
    store16(scr + W * 1024,       aR[o1 >> 1][o1 & 1], lane);
    store16(scr + (4 + W) * 1024, aR[o2 >> 1][o2 & 1], lane);
    syncb();
    oR = aR[W >> 1][W & 1];
    add16(oR, scr + o1 * 1024, lane);
    add16(oR, scr + (4 + o2) * 1024, lane);
    syncb();
    store16(scr + W * 1024, aR[o3 >> 1][o3 & 1], lane);
    syncb();
    add16(oR, scr + o3 * 1024, lane);
    syncb();
    store16(scr + W * 1024,       aL[o1 >> 1][o1 & 1], lane);
    store16(scr + (4 + W) * 1024, aL[o2 >> 1][o2 & 1], lane);
    syncb();
    oL = aL[W >> 1][W & 1];
    add16(oL, scr + o1 * 1024, lane);
    add16(oL, scr + (4 + o2) * 1024, lane);
    syncb();
    store16(scr + W * 1024, aL[o3 >> 1][o3 & 1], lane);
    syncb();
    add16(oL, scr + o3 * 1024, lane);
}

// ---------------- preprocessing: prep transpose + proj matrices (convs now fused into k_big) ----------------
__global__ __launch_bounds__(256) void k_pre(
    const float* __restrict__ cur, const float* __restrict__ pre,
    const float* __restrict__ r_proj_s, const float* __restrict__ r_proj_t,
    const float* __restrict__ node_pj, const float* __restrict__ spa_pj,
    const float* __restrict__ tmp_pj, const float* __restrict__ theta_w,
    __bf16* __restrict__ cur_bf, __bf16* __restrict__ curT, __bf16* __restrict__ preT,
    __bf16* __restrict__ pTs, __bf16* __restrict__ pTt, __bf16* __restrict__ pTn,
    __bf16* __restrict__ pTspa, __bf16* __restrict__ pTtmp, __bf16* __restrict__ thetaBf) {
    __shared__ unsigned short tile[64][72];
    const int b = blockIdx.x, t = threadIdx.x;
    if (b < 512) {
        // ---- prep: 64x64 transpose tiles; cur/pre -> bf16 (+T) ----
        const int x = b & 63, y = (b >> 6) & 3, z = b >> 8;
        const int i0 = x * 64, d0 = y * 64;
        const float* src = z ? pre : cur;
        __bf16* dstT = z ? preT : curT;
        const int r = t >> 2, c4 = (t & 3) * 16;
        const float* srow = src + (size_t)(i0 + r) * DD + d0 + c4;
        alignas(16) unsigned short loc[16];
#pragma unroll
        for (int e = 0; e < 4; ++e) {
            float4 v = ((const float4*)srow)[e];
            loc[e * 4 + 0] = bfbits(v.x);
            loc[e * 4 + 1] = bfbits(v.y);
            loc[e * 4 + 2] = bfbits(v.z);
            loc[e * 4 + 3] = bfbits(v.w);
        }
#pragma unroll
        for (int e = 0; e < 16; ++e) tile[r][c4 + e] = loc[e];
        if (z == 0) {
            __bf16* drow = cur_bf + (size_t)(i0 + r) * DD + d0 + c4;
            *(uint4*)drow = *(uint4*)&loc[0];
            *(uint4*)(drow + 8) = *(uint4*)&loc[8];
        }
        __syncthreads();
        alignas(16) unsigned short o[16];
#pragma unroll
        for (int e = 0; e < 16; ++e) o[e] = tile[c4 + e][r];
        __bf16* trow = dstT + (size_t)(d0 + r) * NN + i0 + c4;
        *(uint4*)trow = *(uint4*)&o[0];
        *(uint4*)(trow + 8) = *(uint4*)&o[8];
    } else {
        // ---- proj matrices -> bf16 (transposed for id<5) ----
        const int bb = b - 512;
        const int id = bb >> 8, r = bb & 255;
        const float* src = id == 0 ? r_proj_s : id == 1 ? r_proj_t : id == 2 ? node_pj
                         : id == 3 ? spa_pj : id == 4 ? tmp_pj : theta_w;
        __bf16* dst = id == 0 ? pTs : id == 1 ? pTt : id == 2 ? pTn
                    : id == 3 ? pTspa : id == 4 ? pTtmp : thetaBf;
        float v = src[r * DD + t];
        if (id < 5) dst[t * DD + r] = (__bf16)v;
        else        dst[r * DD + t] = (__bf16)v;
    }
}

// ---------------- k_big helpers: inline f32 A staging (conv fused) ----------------
// ZS=0: temporal, aligned f32 rows of inc_t. ZS=1: spatial, scattered zero-diag view of
// inc_s (idx = k - (k>i), diag->0), unaligned rows -> scalar dword loads.
template <int ZS>
__device__ inline void loadApair(float (&x)[32], const float* rowp, int i, int kt0, int sc16) {
#pragma unroll
    for (int u = 0; u < 2; ++u) {
        const int c0 = (kt0 + u) * 64 + sc16;
        if (ZS == 0) {
#pragma unroll
            for (int j4 = 0; j4 < 4; ++j4) {
                float4 v = *(const float4*)(rowp + c0 + 4 * j4);
                x[u * 16 + 4 * j4 + 0] = v.x;
                x[u * 16 + 4 * j4 + 1] = v.y;
                x[u * 16 + 4 * j4 + 2] = v.z;
                x[u * 16 + 4 * j4 + 3] = v.w;
            }
        } else {
#pragma unroll
            for (int j = 0; j < 16; ++j) {
                const int k = c0 + j;
                const int dg = (k == i);
                int idx = dg ? 0 : (k - (k > i));
                float v = rowp[idx];
                x[u * 16 + j] = dg ? 0.f : v;
            }
        }
    }
}

// convert pair to bf16, accumulate relu-rowsum / |x| / x^2 partials, swizzled LDS write
__device__ inline void writeApair(const float (&x)[32], __bf16 (*A0)[64], __bf16 (*A1)[64],
                                  int sr, int pc0, int pc1,
                                  float& rs, float& as, float& qs) {
#pragma unroll
    for (int u = 0; u < 2; ++u) {
        __bf16 (*Ab)[64] = u ? A1 : A0;
        alignas(16) unsigned short o[16];
#pragma unroll
        for (int j = 0; j < 16; ++j) {
            float fv = x[u * 16 + j];
            as += fabsf(fv); qs += fv * fv; rs += fmaxf(fv, 0.f);
            o[j] = bfbits(fv);
        }
        *(uint4*)&Ab[sr][pc0] = *(uint4*)&o[0];
        *(uint4*)&Ab[sr][pc1] = *(uint4*)&o[8];
    }
}

template <int ZS>
__device__ inline void iter_body(int P, float (&x)[32],
                                 __bf16 (*A0)[64], __bf16 (*A1)[64],
                                 __bf16 (*B0)[64], __bf16 (*B1)[64],
                                 const float* rowp, int i, int sc16, int sr, int pc0, int pc1,
                                 const __bf16* gB0, const __bf16* gB1,
                                 __bf16* dB0a, __bf16* dB0b, __bf16* dB1a, __bf16* dB1b,
                                 int fr, int swc,
                                 f32x16 (&accR)[2][2], f32x16 (&accL)[2][2],
                                 float& rs, float& as, float& qs) {
    // a: fragment reads for pair P
    bf16x8 a[2][2], bb[2][2];
#pragma unroll
    for (int mi = 0; mi < 2; ++mi) {
        a[0][mi]  = *(const bf16x8*)&A0[mi * 32 + fr][swc];
        a[1][mi]  = *(const bf16x8*)&A1[mi * 32 + fr][swc];
        bb[0][mi] = *(const bf16x8*)&B0[mi * 32 + fr][swc];
        bb[1][mi] = *(const bf16x8*)&B1[mi * 32 + fr][swc];
    }
    asm volatile("s_waitcnt lgkmcnt(0)" ::: "memory");
    __builtin_amdgcn_sched_barrier(0);
    __builtin_amdgcn_s_barrier();                         // bufs of pair P free
    __builtin_amdgcn_sched_barrier(0);
    // g: MFMA on pair P (overlaps the vmcnt wait below)
    __builtin_amdgcn_s_setprio(1);
#pragma unroll
    for (int u = 0; u < 2; ++u)
#pragma unroll
        for (int mi = 0; mi < 2; ++mi) {
            bf16x8 ar = brelu(a[u][mi]);
#pragma unroll
            for (int ni = 0; ni < 2; ++ni) {
                accR[mi][ni] = MFMA32(a[u][mi], bb[u][ni], accR[mi][ni]);
                accL[mi][ni] = MFMA32(ar,       bb[u][ni], accL[mi][ni]);
            }
        }
    __builtin_amdgcn_s_setprio(0);
    __builtin_amdgcn_sched_barrier(0);
    // d: counted wait — A-regs(P+2) + B-DMA(P+1) landed; A(P+3) still in flight
    if (P < 29) {
        if (ZS) asm volatile("s_waitcnt vmcnt(32)" ::: "memory");
        else    asm volatile("s_waitcnt vmcnt(8)"  ::: "memory");
    } else {
        asm volatile("s_waitcnt vmcnt(0)" ::: "memory");
    }
    __builtin_amdgcn_sched_barrier(0);
    if (P < 30) {
        // e: convert+partials+ds_write A(P+2) into freed bufs
        writeApair(x, A0, A1, sr, pc0, pc1, rs, as, qs);
        // f: B-DMA(P+2)
        const size_t tb = (size_t)(2 * (P + 2)) * 64;
        GLD16(gB0 + tb, dB0a);      GLD16(gB1 + tb, dB0b);
        GLD16(gB0 + tb + 64, dB1a); GLD16(gB1 + tb + 64, dB1b);
    }
    __builtin_amdgcn_sched_barrier(0);                    // keep f's DMA older than h's loads
    // h: issue A-global loads for pair P+4 into the just-freed reg set
    if (P < 28) loadApair<ZS>(x, rowp, i, 2 * (P + 4), sc16);
    asm volatile("s_waitcnt lgkmcnt(0)" ::: "memory");    // own ds_writes drained
    __builtin_amdgcn_sched_barrier(0);
    __builtin_amdgcn_s_barrier();
}

template <int ZS>
__device__ inline void run_loop(const float* rowp, int i, const __bf16* BT, int n0, int t,
                                char* smraw,
                                f32x16 (&accR)[2][2], f32x16 (&accL)[2][2],
                                float& rs, float& as, float& qs) {
    __bf16 (*As)[64][64] = (__bf16 (*)[64][64])smraw;            // 4 A bufs, 32 KB
    __bf16 (*Bs)[64][64] = (__bf16 (*)[64][64])(smraw + 32768);  // 4 B bufs, 32 KB
    const int w = t >> 6, lane = t & 63;
    const int sr = t >> 2, c4 = t & 3, sc16 = c4 * 16;
    // B staging addressing (wave w stages row-chunks 2w,2w+1; source pre-XOR'd by row)
    const int lr = lane >> 3, lc = lane & 7;
    const int q0 = 2 * w, q1 = q0 + 1;
    const int csw = (lc ^ lr) * 8;
    const __bf16* gB0 = BT + (size_t)(n0 + 8 * q0 + lr) * NN + csw;
    const __bf16* gB1 = BT + (size_t)(n0 + 8 * q1 + lr) * NN + csw;
    // fragment addressing (32x32x16): row fr(+32mi), k-chunk (2w+h) XOR row
    const int fr = lane & 31, h = lane >> 5;
    const int swc = ((2 * w + h) ^ (fr & 7)) * 8;
    // A write addressing: row sr, logical chunks 2c4,2c4+1 -> XOR by row
    const int pc0 = ((2 * c4) ^ (sr & 7)) * 8;
    const int pc1 = ((2 * c4 + 1) ^ (sr & 7)) * 8;
    float x0[32], x1[32];
    // ---- prologue: pairs 0,1 to LDS; pairs 2,3 loads in flight ----
    loadApair<ZS>(x0, rowp, i, 0, sc16);
    loadApair<ZS>(x1, rowp, i, 2, sc16);
    GLD16(gB0, &Bs[0][8 * q0][0]);            GLD16(gB1, &Bs[0][8 * q1][0]);
    GLD16(gB0 + 64, &Bs[1][8 * q0][0]);       GLD16(gB1 + 64, &Bs[1][8 * q1][0]);
    GLD16(gB0 + 128, &Bs[2][8 * q0][0]);      GLD16(gB1 + 128, &Bs[2][8 * q1][0]);
    GLD16(gB0 + 192, &Bs[3][8 * q0][0]);      GLD16(gB1 + 192, &Bs[3][8 * q1][0]);
    asm volatile("s_waitcnt vmcnt(0)" ::: "memory");
    __builtin_amdgcn_sched_barrier(0);
    writeApair(x0, As[0], As[1], sr, pc0, pc1, rs, as, qs);
    writeApair(x1, As[2], As[3], sr, pc0, pc1, rs, as, qs);
    __builtin_amdgcn_sched_barrier(0);
    loadApair<ZS>(x0, rowp, i, 4, sc16);
    loadApair<ZS>(x1, rowp, i, 6, sc16);
    asm volatile("s_waitcnt lgkmcnt(0)" ::: "memory");
    __builtin_amdgcn_sched_barrier(0);
    __builtin_amdgcn_s_barrier();
    // ---- 16 double-iterations (32 pairs = 64 K-tiles) ----
    for (int q = 0; q < 16; ++q) {
        iter_body<ZS>(2 * q, x0, As[0], As[1], Bs[0], Bs[1], rowp, i, sc16, sr, pc0, pc1,
                      gB0, gB1, &Bs[0][8 * q0][0], &Bs[0][8 * q1][0],
                      &Bs[1][8 * q0][0], &Bs[1][8 * q1][0], fr, swc, accR, accL, rs, as, qs);
        iter_body<ZS>(2 * q + 1, x1, As[2], As[3], Bs[2], Bs[3], rowp, i, sc16, sr, pc0, pc1,
                      gB0, gB1, &Bs[2][8 * q0][0], &Bs[2][8 * q1][0],
                      &Bs[3][8 * q0][0], &Bs[3][8 * q1][0], fr, swc, accR, accL, rs, as, qs);
    }
}

// ---------------- big dual GEMM with fused conv (f32 inc staged+converted inline) ----------------
__global__ __launch_bounds__(256, 2) void k_big(const float* __restrict__ inc_t,
                                                const float* __restrict__ inc_s,
                                                const __bf16* __restrict__ preT,
                                                const __bf16* __restrict__ curT,
                                                const float* __restrict__ negMt,
                                                const float* __restrict__ negMs,
                                                const float* __restrict__ cur,
                                                __bf16* __restrict__ embT, __bf16* __restrict__ embS,
                                                float* __restrict__ pDiff,
                                                float* __restrict__ pAbs2, float* __restrict__ pSq2) {
    const int flat = blockIdx.x + 4 * (blockIdx.y + 64 * blockIdx.z);
    const int swz = (flat & 7) * 64 + (flat >> 3);
    const int bx = swz & 3, by = (swz >> 2) & 63, z = swz >> 8;
    const __bf16* BT  = z ? curT : preT;
    const float* negM = z ? negMs : negMt;
    __bf16* emb       = z ? embS : embT;
    const int n0 = bx * 64, m0 = by * 64;
    __shared__ __align__(16) char smraw[65536];
    f32x16 accR[2][2], accL[2][2];
#pragma unroll
    for (int i = 0; i < 2; ++i)
#pragma unroll
        for (int j = 0; j < 2; ++j) { accR[i][j] = (f32x16)0.f; accL[i][j] = (f32x16)0.f; }
    const int t = threadIdx.x, w = t >> 6, lane = t & 63;
    const int sr = t >> 2;
    const int gi = m0 + sr;                               // this thread's staged row
    float rs = 0.f, as = 0.f, qs = 0.f;
    if (z == 0) {
        run_loop<0>(inc_t + (size_t)gi * NN, gi, BT, n0, t, smraw, accR, accL, rs, as, qs);
    } else {
        run_loop<1>(inc_s + (size_t)gi * (NN - 1), gi, BT, n0, t, smraw, accR, accL, rs, as, qs);
    }
    // ---- per-row rowsum to LDS (4 adjacent lanes share row sr) + panel |x|,x^2 partials ----
    rs += __shfl_xor(rs, 1, 64);
    rs += __shfl_xor(rs, 2, 64);
    float* rs_lds = (float*)(smraw + 32768);              // Bs region, free after loop
    float (*red2)[4] = (float (*)[4])(smraw + 32768 + 256);
    float* sredp = (float*)(smraw + 32768 + 304);
    if ((t & 3) == 0) rs_lds[sr] = rs;
    as = wave_red(as); qs = wave_red(qs);
    if (lane == 0) { red2[0][w] = as; red2[1][w] = qs; }
    __syncthreads();
    if (bx == 0 && t == 0) {
        pAbs2[z * 64 + by] = red2[0][0] + red2[0][1] + red2[0][2] + red2[0][3];
        pSq2 [z * 64 + by] = red2[1][0] + red2[1][1] + red2[1][2] + red2[1][3];
    }
    // ---- cross-wave K-split reduce: wave w owns quadrant (w>>1, w&1) ----
    float* scr = (float*)smraw;                           // As region scratch (32 KB)
    f32x16 oR, oL;
    if      (w == 0) red_owner<0>(accR, accL, scr, lane, oR, oL);
    else if (w == 1) red_owner<1>(accR, accL, scr, lane, oR, oL);
    else if (w == 2) red_owner<2>(accR, accL, scr, lane, oR, oL);
    else             red_owner<3>(accR, accL, scr, lane, oR, oL);
    const int mi = w >> 1, ni = w & 1;
    const int fr = lane & 31, h = lane >> 5;
    float sumd = 0.f;
#pragma unroll
    for (int reg = 0; reg < 16; ++reg) {
        const int rr = (reg & 3) + 8 * (reg >> 2) + 4 * h;
        const int gr = m0 + mi * 32 + rr;
        const int gc = n0 + ni * 32 + fr;
        const size_t idx = (size_t)gr * DD + gc;
        float diff = oR[reg] + negM[idx];                 // recon - master
        sumd += diff * diff;
        float inv = 1.f / (rs_lds[gr - m0] + 1.f);
        emb[idx] = (__bf16)((oL[reg] + cur[idx]) * inv);  // normalized edge emb
    }
    sumd = wave_red(sumd);
    if (lane == 0) sredp[w] = sumd;
    __syncthreads();
    if (t == 0)
        pDiff[z * 256 + by * 4 + bx] = sredp[0] + sredp[1] + sredp[2] + sredp[3];
}

// ---------------- shared MFMA inner step for the small (padded-LDS) GEMMs ----------------
__device__ inline void mfma_step_s(const __bf16 (&As)[64][72], const __bf16 (&Bs)[64][72],
                                   int wr, int wc, int quad, int l16,
                                   f32x4 (&accR)[2][2]) {
#pragma unroll
    for (int ks = 0; ks < 2; ++ks) {
        const int kc = ks * 32 + quad * 8;
        bf16x8 a0 = *(const bf16x8*)&As[wr * 32 + l16][kc];
        bf16x8 a1 = *(const bf16x8*)&As[wr * 32 + 16 + l16][kc];
        bf16x8 b0 = *(const bf16x8*)&Bs[wc * 32 + l16][kc];
        bf16x8 b1 = *(const bf16x8*)&Bs[wc * 32 + 16 + l16][kc];
        accR[0][0] = MFMA16(a0, b0, accR[0][0]);
        accR[0][1] = MFMA16(a0, b1, accR[0][1]);
        accR[1][0] = MFMA16(a1, b0, accR[1][0]);
        accR[1][1] = MFMA16(a1, b1, accR[1][1]);
    }
}

// ---------------- small GEMMs: -master_s, -master_t, node_fea ----------------
__global__ __launch_bounds__(256) void k_small3(const __bf16* __restrict__ cur_bf,
                                                const __bf16* __restrict__ pTs, const __bf16* __restrict__ pTt,
                                                const __bf16* __restrict__ pTn,
                                                float* __restrict__ negMs, float* __restrict__ negMt,
                                                float* __restrict__ nodeFea) {
    const int z = blockIdx.z;
    const __bf16* BT = z == 0 ? pTs : (z == 1 ? pTt : pTn);
    const int n0 = blockIdx.x * 64, m0 = blockIdx.y * 64;
    __shared__ __bf16 As[64][72], Bs[64][72];
    f32x4 accR[2][2];
#pragma unroll
    for (int i = 0; i < 2; ++i)
#pragma unroll
        for (int j = 0; j < 2; ++j) accR[i][j] = (f32x4)0.f;
    const int t = threadIdx.x, w = t >> 6, lane = t & 63, quad = lane >> 4, l16 = lane & 15;
    const int wr = w >> 1, wc = w & 1;
    const int sr = t >> 2, sc = (t & 3) * 16;
    const __bf16* gA = cur_bf + (size_t)(m0 + sr) * DD + sc;
    const __bf16* gB = BT + (size_t)(n0 + sr) * DD + sc;
    for (int kt = 0; kt < DD / 64; ++kt) {
        uint4 av0 = *(const uint4*)(gA);
        uint4 av1 = *(const uint4*)(gA + 8);
        uint4 bv0 = *(const uint4*)(gB);
        uint4 bv1 = *(const uint4*)(gB + 8);
        __syncthreads();
        *(uint4*)&As[sr][sc] = av0; *(uint4*)&As[sr][sc + 8] = av1;
        *(uint4*)&Bs[sr][sc] = bv0; *(uint4*)&Bs[sr][sc + 8] = bv1;
        __syncthreads();
        mfma_step_s(As, Bs, wr, wc, quad, l16, accR);
        gA += 64; gB += 64;
    }
#pragma unroll
    for (int mi = 0; mi < 2; ++mi)
#pragma unroll
        for (int ni = 0; ni < 2; ++ni)
#pragma unroll
            for (int r = 0; r < 4; ++r) {
                int gr = m0 + wr * 32 + mi * 16 + quad * 4 + r;
                int gc = n0 + wc * 32 + ni * 16 + l16;
                size_t idx = (size_t)gr * DD + gc;
                float v = accR[mi][ni][r];
                if (z == 0) negMs[idx] = -v;
                else if (z == 1) negMt[idx] = -v;
                else nodeFea[idx] = v;
            }
}

// ---------------- edge-feature projections + fused attention partial dots ----------------
__global__ __launch_bounds__(256) void k_fea(const __bf16* __restrict__ embS, const __bf16* __restrict__ embT,
                                             const __bf16* __restrict__ pTspa, const __bf16* __restrict__ pTtmp,
                                             const float* __restrict__ nodeF,
                                             float* __restrict__ spaF, float* __restrict__ tmpF,
                                             float* __restrict__ pSpa, float* __restrict__ pTmp) {
    const int z = blockIdx.z;
    const __bf16* Ae = z ? embT : embS;
    const __bf16* BT = z ? pTtmp : pTspa;
    float* outF = z ? tmpF : spaF;
    float* pOut = z ? pTmp : pSpa;
    const int n0 = blockIdx.x * 64, m0 = blockIdx.y * 64;
    __shared__ __bf16 As[64][72], Bs[64][72];
    f32x4 accR[2][2];
#pragma unroll
    for (int i = 0; i < 2; ++i)
#pragma unroll
        for (int j = 0; j < 2; ++j) accR[i][j] = (f32x4)0.f;
    const int t = threadIdx.x, w = t >> 6, lane = t & 63, quad = lane >> 4, l16 = lane & 15;
    const int wr = w >> 1, wc = w & 1;
    const int sr = t >> 2, sc = (t & 3) * 16;
    const __bf16* gA = Ae + (size_t)(m0 + sr) * DD + sc;
    const __bf16* gB = BT + (size_t)(n0 + sr) * DD + sc;
    for (int kt = 0; kt < DD / 64; ++kt) {
        uint4 av0 = *(const uint4*)(gA);
        uint4 av1 = *(const uint4*)(gA + 8);
        uint4 bv0 = *(const uint4*)(gB);
        uint4 bv1 = *(const uint4*)(gB + 8);
        __syncthreads();
        *(uint4*)&As[sr][sc] = av0; *(uint4*)&As[sr][sc + 8] = av1;
        *(uint4*)&Bs[sr][sc] = bv0; *(uint4*)&Bs[sr][sc + 8] = bv1;
        __syncthreads();
        mfma_step_s(As, Bs, wr, wc, quad, l16, accR);
        gA += 64; gB += 64;
    }
    const int slice = blockIdx.x * 2 + wc;
#pragma unroll
    for (int mi = 0; mi < 2; ++mi)
#pragma unroll
        for (int r = 0; r < 4; ++r) {
            const int gr = m0 + wr * 32 + mi * 16 + quad * 4 + r;
            float s = 0.f;
#pragma unroll
            for (int ni = 0; ni < 2; ++ni) {
                const int gc = n0 + wc * 32 + ni * 16 + l16;
                const size_t idx = (size_t)gr * DD + gc;
                const float v = accR[mi][ni][r];
                outF[idx] = v;
                s += v * nodeF[idx];
            }
            s += __shfl_xor(s, 1, 64);
            s += __shfl_xor(s, 2, 64);
            s += __shfl_xor(s, 4, 64);
            s += __shfl_xor(s, 8, 64);
            if (l16 == 0) pOut[(size_t)slice * NN + gr] = s;
        }
}

// ---------------- final: val @ theta_w^T + b, relu -> d_out (+ fused loss in block 0) ----------------
__global__ __launch_bounds__(256) void k_final(const float* __restrict__ spaF, const float* __restrict__ tmpF,
                                               const float* __restrict__ pSpa, const float* __restrict__ pTmp,
                                               const __bf16* __restrict__ thetaBf, const float* __restrict__ thetaB,
                                               const float* __restrict__ pAbs2, const float* __restrict__ pSq2,
                                               const float* __restrict__ pDiff,
                                               float* __restrict__ out) {
    const int n0 = blockIdx.x * 64, m0 = blockIdx.y * 64;
    __shared__ __bf16 As[64][72], Bs[64][72];
    f32x4 accR[2][2];
#pragma unroll
    for (int i = 0; i < 2; ++i)
#pragma unroll
        for (int j = 0; j < 2; ++j) accR[i][j] = (f32x4)0.f;
    const int t = threadIdx.x, w = t >> 6, lane = t & 63, quad = lane >> 4, l16 = lane & 15;
    const int wr = w >> 1, wc = w & 1;
    const int sr = t >> 2, sc = (t & 3) * 16;
    const int row = m0 + sr;
    float sa = 0.f, ta = 0.f;
#pragma unroll
    for (int j = 0; j < 8; ++j) {
        sa += pSpa[(size_t)j * NN + row];
        ta += pTmp[(size_t)j * NN + row];
    }
    sa *= 0.0625f; ta *= 0.0625f;   // 1/sqrt(256)
    const float* gS = spaF + (size_t)row * DD + sc;
    const float* gT = tmpF + (size_t)row * DD + sc;
    const __bf16* gB = thetaBf + (size_t)(n0 + sr) * DD + sc;
    for (int kt = 0; kt < DD / 64; ++kt) {
        __bf16 tmp[16];
#pragma unroll
        for (int e4 = 0; e4 < 4; ++e4) {
            float4 vs = ((const float4*)gS)[e4];
            float4 vt = ((const float4*)gT)[e4];
            tmp[e4 * 4 + 0] = (__bf16)(sa * vs.x + ta * vt.x);
            tmp[e4 * 4 + 1] = (__bf16)(sa * vs.y + ta * vt.y);
            tmp[e4 * 4 + 2] = (__bf16)(sa * vs.z + ta * vt.z);
            tmp[e4 * 4 + 3] = (__bf16)(sa * vs.w + ta * vt.w);
        }
        uint4 bv0 = *(const uint4*)(gB);
        uint4 bv1 = *(const uint4*)(gB + 8);
        __syncthreads();
        *(uint4*)&As[sr][sc] = *(uint4*)&tmp[0]; *(uint4*)&As[sr][sc + 8] = *(uint4*)&tmp[8];
        *(uint4*)&Bs[sr][sc] = bv0; *(uint4*)&Bs[sr][sc + 8] = bv1;
        __syncthreads();
        mfma_step_s(As, Bs, wr, wc, quad, l16, accR);
        gS += 64; gT += 64; gB += 64;
    }
#pragma unroll
    for (int mi = 0; mi < 2; ++mi)
#pragma unroll
        for (int ni = 0; ni < 2; ++ni)
#pragma unroll
            for (int r = 0; r < 4; ++r) {
                int gr = m0 + wr * 32 + mi * 16 + quad * 4 + r;
                int gc = n0 + wc * 32 + ni * 16 + l16;
                float v = accR[mi][ni][r] + thetaB[gc];
                out[(size_t)gr * DD + gc] = fmaxf(v, 0.f);
            }
    // ---- fused loss (one block) ----
    if (blockIdx.x == 0 && blockIdx.y == 0) {
        float aT = 0.f, qT = 0.f, aS = 0.f, qS = 0.f;
        if (t < 64) { aT = pAbs2[t]; qT = pSq2[t]; aS = pAbs2[64 + t]; qS = pSq2[64 + t]; }
        float dT = pDiff[t], dS = pDiff[256 + t];
        aT = wave_red(aT); qT = wave_red(qT); aS = wave_red(aS); qS = wave_red(qS);
        dT = wave_red(dT); dS = wave_red(dS);
        float (*red)[4] = (float (*)[4])As;
        if (lane == 0) { red[0][w] = aT; red[1][w] = qT; red[2][w] = aS; red[3][w] = qS; red[4][w] = dT; red[5][w] = dS; }
        __syncthreads();
        if (t == 0) {
            float s[6];
#pragma unroll
            for (int k = 0; k < 6; ++k) s[k] = red[k][0] + red[k][1] + red[k][2] + red[k][3];
            float l = s[0] + 0.001f * sqrtf(s[1]) + 0.2f * sqrtf(s[4])    // temporal
                    + s[2] + 0.001f * sqrtf(s[3]) + 0.2f * sqrtf(s[5]);   // spatial
            out[(size_t)NN * DD] = l;
        }
    }
}

extern "C" void kernel_launch(void* const* d_in, const int* in_sizes, int n_in,
                              void* d_out, int out_size, void* d_ws, size_t ws_size,
                              hipStream_t stream) {
    (void)in_sizes; (void)n_in; (void)out_size; (void)ws_size;
    const float* cur      = (const float*)d_in[0];
    const float* pre      = (const float*)d_in[1];
    const float* r_proj_s = (const float*)d_in[2];
    const float* inc_s    = (const float*)d_in[3];
    const float* r_proj_t = (const float*)d_in[4];
    const float* inc_t    = (const float*)d_in[5];
    const float* node_pj  = (const float*)d_in[6];
    const float* spa_pj   = (const float*)d_in[7];
    const float* tmp_pj   = (const float*)d_in[8];
    const float* theta_w  = (const float*)d_in[9];
    const float* theta_b  = (const float*)d_in[10];
    float* out = (float*)d_out;

    char* p = (char*)d_ws;
    auto alloc = [&](size_t bytes) -> void* {
        void* r = (void*)p;
        p += (bytes + 255) & ~(size_t)255;
        return r;
    };
    __bf16* cur_bf  = (__bf16*)alloc((size_t)NN * DD * 2);
    __bf16* curT    = (__bf16*)alloc((size_t)NN * DD * 2);
    __bf16* preT    = (__bf16*)alloc((size_t)NN * DD * 2);
    __bf16* pTs     = (__bf16*)alloc((size_t)DD * DD * 2);
    __bf16* pTt     = (__bf16*)alloc((size_t)DD * DD * 2);
    __bf16* pTn     = (__bf16*)alloc((size_t)DD * DD * 2);
    __bf16* pTspa   = (__bf16*)alloc((size_t)DD * DD * 2);
    __bf16* pTtmp   = (__bf16*)alloc((size_t)DD * DD * 2);
    __bf16* thetaBf = (__bf16*)alloc((size_t)DD * DD * 2);
    __bf16* embS    = (__bf16*)alloc((size_t)NN * DD * 2);
    __bf16* embT    = (__bf16*)alloc((size_t)NN * DD * 2);
    float* negMs    = (float*)alloc((size_t)NN * DD * 4);
    float* negMt    = (float*)alloc((size_t)NN * DD * 4);
    float* nodeFea  = (float*)alloc((size_t)NN * DD * 4);
    float* spaF     = (float*)alloc((size_t)NN * DD * 4);
    float* tmpF     = (float*)alloc((size_t)NN * DD * 4);
    float* pSpa     = (float*)alloc((size_t)8 * NN * 4);
    float* pTmp     = (float*)alloc((size_t)8 * NN * 4);
    float* pAbs2    = (float*)alloc(128 * 4);
    float* pSq2     = (float*)alloc(128 * 4);
    float* pDiff    = (float*)alloc(512 * 4);

    k_pre<<<2048, 256, 0, stream>>>(cur, pre, r_proj_s, r_proj_t, node_pj, spa_pj, tmp_pj, theta_w,
                                    cur_bf, curT, preT, pTs, pTt, pTn, pTspa, pTtmp, thetaBf);
    k_small3<<<dim3(4, 64, 3), 256, 0, stream>>>(cur_bf, pTs, pTt, pTn, negMs, negMt, nodeFea);
    k_big<<<dim3(4, 64, 2), 256, 0, stream>>>(inc_t, inc_s, preT, curT, negMt, negMs, cur,
                                              embT, embS, pDiff, pAbs2, pSq2);
    k_fea<<<dim3(4, 64, 2), 256, 0, stream>>>(embS, embT, pTspa, pTtmp, nodeFea,
                                              spaF, tmpF, pSpa, pTmp);
    k_final<<<dim3(4, 64), 256, 0, stream>>>(spaF, tmpF, pSpa, pTmp, thetaBf, theta_b,
                                             pAbs2, pSq2, pDiff, out);
}

// Round 5
// 262.027 us; speedup vs baseline: 1.9364x; 1.9364x over previous
//
#include <hip/hip_runtime.h>
#include <hip/hip_bf16.h>
#include <math.h>

#define NN 4096
#define DD 256

typedef __bf16 bf16x8 __attribute__((ext_vector_type(8)));
typedef short  short8 __attribute__((ext_vector_type(8)));
typedef float  f32x4  __attribute__((ext_vector_type(4)));
typedef float  f32x16 __attribute__((ext_vector_type(16)));

typedef __attribute__((address_space(1))) const void gv_t;
typedef __attribute__((address_space(3))) void lv_t;
#define GLD16(gp, lp) __builtin_amdgcn_global_load_lds((gv_t*)(gp), (lv_t*)(lp), 16, 0, 0)

#define MFMA16(a, b, c) __builtin_amdgcn_mfma_f32_16x16x32_bf16((a), (b), (c), 0, 0, 0)
#define MFMA32(a, b, c) __builtin_amdgcn_mfma_f32_32x32x16_bf16((a), (b), (c), 0, 0, 0)

__device__ inline bf16x8 brelu(bf16x8 a) {
    short8 s = __builtin_bit_cast(short8, a);
    s = s & ~(s >> 15);            // negative (sign bit set) -> 0, else keep
    return __builtin_bit_cast(bf16x8, s);
}

__device__ inline float wave_red(float v) {
#pragma unroll
    for (int o = 32; o > 0; o >>= 1) v += __shfl_down(v, o, 64);
    return v;
}

__device__ inline unsigned short bfbits(float f) {
    return __builtin_bit_cast(unsigned short, (__bf16)f);
}

__device__ inline void syncb() {
    asm volatile("s_waitcnt lgkmcnt(0)" ::: "memory");
    __builtin_amdgcn_s_barrier();
}

// store/load one 32x32 f32 fragment (16 regs/lane) to a 4KB LDS slot, bank-balanced.
__device__ inline void store16(float* base, const f32x16& v, int lane) {
#pragma unroll
    for (int r4 = 0; r4 < 4; ++r4) {
        f32x4 c = {v[4 * r4], v[4 * r4 + 1], v[4 * r4 + 2], v[4 * r4 + 3]};
        ((f32x4*)base)[r4 * 64 + lane] = c;
    }
}
__device__ inline void add16(f32x16& v, const float* base, int lane) {
#pragma unroll
    for (int r4 = 0; r4 < 4; ++r4) {
        f32x4 c = ((const f32x4*)base)[r4 * 64 + lane];
        v[4 * r4] += c[0]; v[4 * r4 + 1] += c[1]; v[4 * r4 + 2] += c[2]; v[4 * r4 + 3] += c[3];
    }
}

// cross-wave K-split reduction: wave W ends owning quadrant (mi=W>>1, ni=W&1).
template <int W>
__device__ inline void red_owner(f32x16 (&aR)[2][2], f32x16 (&aL)[2][2],
                                 float* scr, int lane, f32x16& oR, f32x16& oL) {
    constexpr int o1 = W ^ 1, o2 = W ^ 2, o3 = W ^ 3;
    store16(scr + W * 1024,       aR[o1 >> 1][o1 & 1], lane);
    store16(scr + (4 + W) * 1024, aR[o2 >> 1][o2 & 1], lane);
    syncb();
    oR = aR[W >> 1][W & 1];
    add16(oR, scr + o1 * 1024, lane);
    add16(oR, scr + (4 + o2) * 1024, lane);
    syncb();
    store16(scr + W * 1024, aR[o3 >> 1][o3 & 1], lane);
    syncb();
    add16(oR, scr + o3 * 1024, lane);
    syncb();
    store16(scr + W * 1024,       aL[o1 >> 1][o1 & 1], lane);
    store16(scr + (4 + W) * 1024, aL[o2 >> 1][o2 & 1], lane);
    syncb();
    oL = aL[W >> 1][W & 1];
    add16(oL, scr + o1 * 1024, lane);
    add16(oL, scr + (4 + o2) * 1024, lane);
    syncb();
    store16(scr + W * 1024, aL[o3 >> 1][o3 & 1], lane);
    syncb();
    add16(oL, scr + o3 * 1024, lane);
}

// ---------------- preprocessing: prep transpose + proj matrices ----------------
__global__ __launch_bounds__(256) void k_pre(
    const float* __restrict__ cur, const float* __restrict__ pre,
    const float* __restrict__ r_proj_s, const float* __restrict__ r_proj_t,
    const float* __restrict__ node_pj, const float* __restrict__ spa_pj,
    const float* __restrict__ tmp_pj, const float* __restrict__ theta_w,
    __bf16* __restrict__ cur_bf, __bf16* __restrict__ curT, __bf16* __restrict__ preT,
    __bf16* __restrict__ pTs, __bf16* __restrict__ pTt, __bf16* __restrict__ pTn,
    __bf16* __restrict__ pTspa, __bf16* __restrict__ pTtmp, __bf16* __restrict__ thetaBf) {
    __shared__ unsigned short tile[64][72];
    const int b = blockIdx.x, t = threadIdx.x;
    if (b < 512) {
        const int x = b & 63, y = (b >> 6) & 3, z = b >> 8;
        const int i0 = x * 64, d0 = y * 64;
        const float* src = z ? pre : cur;
        __bf16* dstT = z ? preT : curT;
        const int r = t >> 2, c4 = (t & 3) * 16;
        const float* srow = src + (size_t)(i0 + r) * DD + d0 + c4;
        alignas(16) unsigned short loc[16];
#pragma unroll
        for (int e = 0; e < 4; ++e) {
            float4 v = ((const float4*)srow)[e];
            loc[e * 4 + 0] = bfbits(v.x);
            loc[e * 4 + 1] = bfbits(v.y);
            loc[e * 4 + 2] = bfbits(v.z);
            loc[e * 4 + 3] = bfbits(v.w);
        }
#pragma unroll
        for (int e = 0; e < 16; ++e) tile[r][c4 + e] = loc[e];
        if (z == 0) {
            __bf16* drow = cur_bf + (size_t)(i0 + r) * DD + d0 + c4;
            *(uint4*)drow = *(uint4*)&loc[0];
            *(uint4*)(drow + 8) = *(uint4*)&loc[8];
        }
        __syncthreads();
        alignas(16) unsigned short o[16];
#pragma unroll
        for (int e = 0; e < 16; ++e) o[e] = tile[c4 + e][r];
        __bf16* trow = dstT + (size_t)(d0 + r) * NN + i0 + c4;
        *(uint4*)trow = *(uint4*)&o[0];
        *(uint4*)(trow + 8) = *(uint4*)&o[8];
    } else {
        const int bb = b - 512;
        const int id = bb >> 8, r = bb & 255;
        const float* src = id == 0 ? r_proj_s : id == 1 ? r_proj_t : id == 2 ? node_pj
                         : id == 3 ? spa_pj : id == 4 ? tmp_pj : theta_w;
        __bf16* dst = id == 0 ? pTs : id == 1 ? pTt : id == 2 ? pTn
                    : id == 3 ? pTspa : id == 4 ? pTtmp : thetaBf;
        float v = src[r * DD + t];
        if (id < 5) dst[t * DD + r] = (__bf16)v;
        else        dst[r * DD + t] = (__bf16)v;
    }
}

// ---------------- k_big A staging: contiguous 16-float window + static-index repair ----------------
// ZS=0: temporal, aligned rows of inc_t, window = [c0, c0+16).
// ZS=1: spatial zero-diag view of inc_s row i: dest[k] = k<i ? src[k] : (k==i ? 0 : src[k-1]).
//       Load window at base = min(c0 - (c0>i), NN-17) (always in-bounds, 4B-aligned),
//       repair with static-index selects (d = c0-base in {0,1}).
template <int ZS>
__device__ inline void loadA(float (&lx)[16], const float* rowp, int i, int tile, int sc16) {
    const int c0 = tile * 64 + sc16;
    if constexpr (ZS == 0) {
#pragma unroll
        for (int j4 = 0; j4 < 4; ++j4)
            *(float4*)&lx[4 * j4] = *(const float4*)(rowp + c0 + 4 * j4);
    } else {
        int base = c0 - (c0 > i);
        if (base > NN - 17) base = NN - 17;
#pragma unroll
        for (int j4 = 0; j4 < 4; ++j4)
            __builtin_memcpy(&lx[4 * j4], rowp + base + 4 * j4, 16);
    }
}

// convert tile to bf16, accumulate relu-rowsum / |x| / x^2 partials, swizzled LDS write
template <int ZS>
__device__ inline void writeA(const float (&lx)[16], __bf16 (*Ab)[64],
                              int i, int tile, int sc16, int sr, int pc0, int pc1,
                              float& rs, float& as, float& qs) {
    const int c0 = tile * 64 + sc16;
    alignas(16) unsigned short o[16];
    if constexpr (ZS == 0) {
#pragma unroll
        for (int j = 0; j < 16; ++j) {
            float fv = lx[j];
            as += fabsf(fv); qs += fv * fv; rs += fmaxf(fv, 0.f);
            o[j] = bfbits(fv);
        }
    } else {
        int base = c0 - (c0 > i);
        if (base > NN - 17) base = NN - 17;
        const int d = c0 - base;   // 0 or 1
#pragma unroll
        for (int j = 0; j < 16; ++j) {
            const int k = c0 + j;
            float alt = d ? ((j < 15) ? lx[j + 1] : 0.f) : lx[j];          // src[k]
            float agt = d ? lx[j] : ((j > 0) ? lx[j - 1] : 0.f);           // src[k-1]
            float fv = (k < i) ? alt : ((k == i) ? 0.f : agt);
            as += fabsf(fv); qs += fv * fv; rs += fmaxf(fv, 0.f);
            o[j] = bfbits(fv);
        }
    }
    *(uint4*)&Ab[sr][pc0] = *(uint4*)&o[0];
    *(uint4*)&Ab[sr][pc1] = *(uint4*)&o[8];
}

// one K-tile iteration: frag-read(P) -> barrier -> MFMA(P) | vmcnt(2) -> writeA(P+1)
// -> issue A(P+2) then B-DMA(P+2) -> lgkm + vmcnt(6) -> barrier.  vmcnt never 0 mid-loop.
template <int ZS>
__device__ inline void one_iter(int P, float (&lx)[16],
                                __bf16 (*Acur)[64], __bf16 (*Bcur)[64], __bf16 (*Anext)[64],
                                __bf16* dB0, __bf16* dB1,
                                const float* rowp, int i, int sc16, int sr, int pc0, int pc1,
                                const __bf16* gB0, const __bf16* gB1,
                                int fr, int swc,
                                f32x16 (&accR)[2][2], f32x16 (&accL)[2][2],
                                float& rs, float& as, float& qs) {
    bf16x8 a[2], bb[2];
    a[0]  = *(const bf16x8*)&Acur[fr][swc];
    a[1]  = *(const bf16x8*)&Acur[32 + fr][swc];
    bb[0] = *(const bf16x8*)&Bcur[fr][swc];
    bb[1] = *(const bf16x8*)&Bcur[32 + fr][swc];
    asm volatile("s_waitcnt lgkmcnt(0)" ::: "memory");
    __builtin_amdgcn_sched_barrier(0);
    __builtin_amdgcn_s_barrier();                         // bufs of tile P free
    __builtin_amdgcn_sched_barrier(0);
    __builtin_amdgcn_s_setprio(1);
#pragma unroll
    for (int mi = 0; mi < 2; ++mi) {
        bf16x8 ar = brelu(a[mi]);
        accR[mi][0] = MFMA32(a[mi], bb[0], accR[mi][0]);
        accR[mi][1] = MFMA32(a[mi], bb[1], accR[mi][1]);
        accL[mi][0] = MFMA32(ar,    bb[0], accL[mi][0]);
        accL[mi][1] = MFMA32(ar,    bb[1], accL[mi][1]);
    }
    __builtin_amdgcn_s_setprio(0);
    __builtin_amdgcn_sched_barrier(0);
    if (P < 63) {
        // A(P+1) regs landed: outstanding = [A(P+1) older, B-DMA(P+1)=2 newest]
        asm volatile("s_waitcnt vmcnt(2)" ::: "memory");
        __builtin_amdgcn_sched_barrier(0);
        writeA<ZS>(lx, Anext, i, P + 1, sc16, sr, pc0, pc1, rs, as, qs);
        __builtin_amdgcn_sched_barrier(0);
        if (P < 62) {
            loadA<ZS>(lx, rowp, i, P + 2, sc16);          // A loads BEFORE B-DMA (count invariant)
            __builtin_amdgcn_sched_barrier(0);
            const size_t ko = (size_t)(P + 2) * 64;
            GLD16(gB0 + ko, dB0);
            GLD16(gB1 + ko, dB1);
        }
        asm volatile("s_waitcnt lgkmcnt(0)" ::: "memory");    // own ds_writes drained
        if (P < 62) asm volatile("s_waitcnt vmcnt(6)" ::: "memory");   // B(P+1) landed
        else        asm volatile("s_waitcnt vmcnt(0)" ::: "memory");
        __builtin_amdgcn_sched_barrier(0);
        __builtin_amdgcn_s_barrier();
        __builtin_amdgcn_sched_barrier(0);
    }
}

template <int ZS>
__device__ inline void run_loop(const float* rowp, int i, const __bf16* BT, int n0, int t,
                                char* smraw,
                                f32x16 (&accR)[2][2], f32x16 (&accL)[2][2],
                                float& rs, float& as, float& qs) {
    __bf16 (*As)[64][64] = (__bf16 (*)[64][64])smraw;            // 2 A bufs, 16 KB
    __bf16 (*Bs)[64][64] = (__bf16 (*)[64][64])(smraw + 16384);  // 2 B bufs, 16 KB
    const int w = t >> 6, lane = t & 63;
    const int sr = t >> 2, c4 = t & 3, sc16 = c4 * 16;
    // B staging addressing (wave w stages row-chunks 2w,2w+1; source pre-XOR'd by row)
    const int lr = lane >> 3, lc = lane & 7;
    const int q0 = 2 * w, q1 = q0 + 1;
    const int csw = (lc ^ lr) * 8;
    const __bf16* gB0 = BT + (size_t)(n0 + 8 * q0 + lr) * NN + csw;
    const __bf16* gB1 = BT + (size_t)(n0 + 8 * q1 + lr) * NN + csw;
    // fragment addressing (32x32x16): row fr(+32mi), k-chunk (2w+h) XOR row
    const int fr = lane & 31, h = lane >> 5;
    const int swc = ((2 * w + h) ^ (fr & 7)) * 8;
    // A write addressing: row sr, logical chunks 2c4,2c4+1 -> XOR by row
    const int pc0 = ((2 * c4) ^ (sr & 7)) * 8;
    const int pc1 = ((2 * c4 + 1) ^ (sr & 7)) * 8;
    float lx[16];
    // ---- prologue: tile 0 -> LDS; tile 1 A-regs + B-DMA in flight ----
    loadA<ZS>(lx, rowp, i, 0, sc16);
    __builtin_amdgcn_sched_barrier(0);
    GLD16(gB0, &Bs[0][8 * q0][0]); GLD16(gB1, &Bs[0][8 * q1][0]);
    asm volatile("s_waitcnt vmcnt(2)" ::: "memory");      // A(0) regs landed
    __builtin_amdgcn_sched_barrier(0);
    writeA<ZS>(lx, As[0], i, 0, sc16, sr, pc0, pc1, rs, as, qs);
    __builtin_amdgcn_sched_barrier(0);
    loadA<ZS>(lx, rowp, i, 1, sc16);
    __builtin_amdgcn_sched_barrier(0);
    GLD16(gB0 + 64, &Bs[1][8 * q0][0]); GLD16(gB1 + 64, &Bs[1][8 * q1][0]);
    asm volatile("s_waitcnt lgkmcnt(0)" ::: "memory");
    asm volatile("s_waitcnt vmcnt(6)" ::: "memory");      // B(0) landed
    __builtin_amdgcn_sched_barrier(0);
    __builtin_amdgcn_s_barrier();
    __builtin_amdgcn_sched_barrier(0);
    // ---- 32 double-iterations (64 K-tiles), compile-time buffer parity ----
    for (int q = 0; q < 32; ++q) {
        one_iter<ZS>(2 * q, lx, As[0], Bs[0], As[1],
                     &Bs[0][8 * q0][0], &Bs[0][8 * q1][0],
                     rowp, i, sc16, sr, pc0, pc1, gB0, gB1, fr, swc, accR, accL, rs, as, qs);
        one_iter<ZS>(2 * q + 1, lx, As[1], Bs[1], As[0],
                     &Bs[1][8 * q0][0], &Bs[1][8 * q1][0],
                     rowp, i, sc16, sr, pc0, pc1, gB0, gB1, fr, swc, accR, accL, rs, as, qs);
    }
}

// ---------------- big dual GEMM with fused conv (f32 inc staged+converted inline) ----------------
__global__ __launch_bounds__(256, 2) void k_big(const float* __restrict__ inc_t,
                                                const float* __restrict__ inc_s,
                                                const __bf16* __restrict__ preT,
                                                const __bf16* __restrict__ curT,
                                                const float* __restrict__ negMt,
                                                const float* __restrict__ negMs,
                                                const float* __restrict__ cur,
                                                __bf16* __restrict__ embT, __bf16* __restrict__ embS,
                                                float* __restrict__ pDiff,
                                                float* __restrict__ pAbs2, float* __restrict__ pSq2) {
    const int flat = blockIdx.x + 4 * (blockIdx.y + 64 * blockIdx.z);
    const int swz = (flat & 7) * 64 + (flat >> 3);
    const int bx = swz & 3, by = (swz >> 2) & 63, z = swz >> 8;
    const __bf16* BT  = z ? curT : preT;
    const float* negM = z ? negMs : negMt;
    __bf16* emb       = z ? embS : embT;
    const int n0 = bx * 64, m0 = by * 64;
    __shared__ __align__(16) char smraw[33280];
    f32x16 accR[2][2], accL[2][2];
#pragma unroll
    for (int i = 0; i < 2; ++i)
#pragma unroll
        for (int j = 0; j < 2; ++j) { accR[i][j] = (f32x16)0.f; accL[i][j] = (f32x16)0.f; }
    const int t = threadIdx.x, w = t >> 6, lane = t & 63;
    const int sr = t >> 2;
    const int gi = m0 + sr;                               // this thread's staged row
    float rs = 0.f, as = 0.f, qs = 0.f;
    if (z == 0) {
        run_loop<0>(inc_t + (size_t)gi * NN, gi, BT, n0, t, smraw, accR, accL, rs, as, qs);
    } else {
        run_loop<1>(inc_s + (size_t)gi * (NN - 1), gi, BT, n0, t, smraw, accR, accL, rs, as, qs);
    }
    // ---- per-row rowsum to LDS (4 adjacent lanes share row sr) + panel |x|,x^2 partials ----
    rs += __shfl_xor(rs, 1, 64);
    rs += __shfl_xor(rs, 2, 64);
    float* rs_lds = (float*)(smraw + 32768);              // beyond buf region
    float (*red2)[4] = (float (*)[4])(smraw + 33024);
    float* sredp = (float*)(smraw + 33056);
    if ((t & 3) == 0) rs_lds[sr] = rs;
    as = wave_red(as); qs = wave_red(qs);
    if (lane == 0) { red2[0][w] = as; red2[1][w] = qs; }
    __syncthreads();
    if (bx == 0 && t == 0) {
        pAbs2[z * 64 + by] = red2[0][0] + red2[0][1] + red2[0][2] + red2[0][3];
        pSq2 [z * 64 + by] = red2[1][0] + red2[1][1] + red2[1][2] + red2[1][3];
    }
    // ---- cross-wave K-split reduce: wave w owns quadrant (w>>1, w&1) ----
    float* scr = (float*)smraw;                           // buf region scratch (32 KB)
    f32x16 oR, oL;
    if      (w == 0) red_owner<0>(accR, accL, scr, lane, oR, oL);
    else if (w == 1) red_owner<1>(accR, accL, scr, lane, oR, oL);
    else if (w == 2) red_owner<2>(accR, accL, scr, lane, oR, oL);
    else             red_owner<3>(accR, accL, scr, lane, oR, oL);
    const int mi = w >> 1, ni = w & 1;
    const int fr = lane & 31, h = lane >> 5;
    float sumd = 0.f;
#pragma unroll
    for (int reg = 0; reg < 16; ++reg) {
        const int rr = (reg & 3) + 8 * (reg >> 2) + 4 * h;
        const int gr = m0 + mi * 32 + rr;
        const int gc = n0 + ni * 32 + fr;
        const size_t idx = (size_t)gr * DD + gc;
        float diff = oR[reg] + negM[idx];                 // recon - master
        sumd += diff * diff;
        float inv = 1.f / (rs_lds[gr - m0] + 1.f);
        emb[idx] = (__bf16)((oL[reg] + cur[idx]) * inv);  // normalized edge emb
    }
    sumd = wave_red(sumd);
    if (lane == 0) sredp[w] = sumd;
    __syncthreads();
    if (t == 0)
        pDiff[z * 256 + by * 4 + bx] = sredp[0] + sredp[1] + sredp[2] + sredp[3];
}

// ---------------- shared MFMA inner step for the small (padded-LDS) GEMMs ----------------
__device__ inline void mfma_step_s(const __bf16 (&As)[64][72], const __bf16 (&Bs)[64][72],
                                   int wr, int wc, int quad, int l16,
                                   f32x4 (&accR)[2][2]) {
#pragma unroll
    for (int ks = 0; ks < 2; ++ks) {
        const int kc = ks * 32 + quad * 8;
        bf16x8 a0 = *(const bf16x8*)&As[wr * 32 + l16][kc];
        bf16x8 a1 = *(const bf16x8*)&As[wr * 32 + 16 + l16][kc];
        bf16x8 b0 = *(const bf16x8*)&Bs[wc * 32 + l16][kc];
        bf16x8 b1 = *(const bf16x8*)&Bs[wc * 32 + 16 + l16][kc];
        accR[0][0] = MFMA16(a0, b0, accR[0][0]);
        accR[0][1] = MFMA16(a0, b1, accR[0][1]);
        accR[1][0] = MFMA16(a1, b0, accR[1][0]);
        accR[1][1] = MFMA16(a1, b1, accR[1][1]);
    }
}

// ---------------- small GEMMs: -master_s, -master_t, node_fea ----------------
__global__ __launch_bounds__(256) void k_small3(const __bf16* __restrict__ cur_bf,
                                                const __bf16* __restrict__ pTs, const __bf16* __restrict__ pTt,
                                                const __bf16* __restrict__ pTn,
                                                float* __restrict__ negMs, float* __restrict__ negMt,
                                                float* __restrict__ nodeFea) {
    const int z = blockIdx.z;
    const __bf16* BT = z == 0 ? pTs : (z == 1 ? pTt : pTn);
    const int n0 = blockIdx.x * 64, m0 = blockIdx.y * 64;
    __shared__ __bf16 As[64][72], Bs[64][72];
    f32x4 accR[2][2];
#pragma unroll
    for (int i = 0; i < 2; ++i)
#pragma unroll
        for (int j = 0; j < 2; ++j) accR[i][j] = (f32x4)0.f;
    const int t = threadIdx.x, w = t >> 6, lane = t & 63, quad = lane >> 4, l16 = lane & 15;
    const int wr = w >> 1, wc = w & 1;
    const int sr = t >> 2, sc = (t & 3) * 16;
    const __bf16* gA = cur_bf + (size_t)(m0 + sr) * DD + sc;
    const __bf16* gB = BT + (size_t)(n0 + sr) * DD + sc;
    for (int kt = 0; kt < DD / 64; ++kt) {
        uint4 av0 = *(const uint4*)(gA);
        uint4 av1 = *(const uint4*)(gA + 8);
        uint4 bv0 = *(const uint4*)(gB);
        uint4 bv1 = *(const uint4*)(gB + 8);
        __syncthreads();
        *(uint4*)&As[sr][sc] = av0; *(uint4*)&As[sr][sc + 8] = av1;
        *(uint4*)&Bs[sr][sc] = bv0; *(uint4*)&Bs[sr][sc + 8] = bv1;
        __syncthreads();
        mfma_step_s(As, Bs, wr, wc, quad, l16, accR);
        gA += 64; gB += 64;
    }
#pragma unroll
    for (int mi = 0; mi < 2; ++mi)
#pragma unroll
        for (int ni = 0; ni < 2; ++ni)
#pragma unroll
            for (int r = 0; r < 4; ++r) {
                int gr = m0 + wr * 32 + mi * 16 + quad * 4 + r;
                int gc = n0 + wc * 32 + ni * 16 + l16;
                size_t idx = (size_t)gr * DD + gc;
                float v = accR[mi][ni][r];
                if (z == 0) negMs[idx] = -v;
                else if (z == 1) negMt[idx] = -v;
                else nodeFea[idx] = v;
            }
}

// ---------------- edge-feature projections + fused attention partial dots ----------------
__global__ __launch_bounds__(256) void k_fea(const __bf16* __restrict__ embS, const __bf16* __restrict__ embT,
                                             const __bf16* __restrict__ pTspa, const __bf16* __restrict__ pTtmp,
                                             const float* __restrict__ nodeF,
                                             float* __restrict__ spaF, float* __restrict__ tmpF,
                                             float* __restrict__ pSpa, float* __restrict__ pTmp) {
    const int z = blockIdx.z;
    const __bf16* Ae = z ? embT : embS;
    const __bf16* BT = z ? pTtmp : pTspa;
    float* outF = z ? tmpF : spaF;
    float* pOut = z ? pTmp : pSpa;
    const int n0 = blockIdx.x * 64, m0 = blockIdx.y * 64;
    __shared__ __bf16 As[64][72], Bs[64][72];
    f32x4 accR[2][2];
#pragma unroll
    for (int i = 0; i < 2; ++i)
#pragma unroll
        for (int j = 0; j < 2; ++j) accR[i][j] = (f32x4)0.f;
    const int t = threadIdx.x, w = t >> 6, lane = t & 63, quad = lane >> 4, l16 = lane & 15;
    const int wr = w >> 1, wc = w & 1;
    const int sr = t >> 2, sc = (t & 3) * 16;
    const __bf16* gA = Ae + (size_t)(m0 + sr) * DD + sc;
    const __bf16* gB = BT + (size_t)(n0 + sr) * DD + sc;
    for (int kt = 0; kt < DD / 64; ++kt) {
        uint4 av0 = *(const uint4*)(gA);
        uint4 av1 = *(const uint4*)(gA + 8);
        uint4 bv0 = *(const uint4*)(gB);
        uint4 bv1 = *(const uint4*)(gB + 8);
        __syncthreads();
        *(uint4*)&As[sr][sc] = av0; *(uint4*)&As[sr][sc + 8] = av1;
        *(uint4*)&Bs[sr][sc] = bv0; *(uint4*)&Bs[sr][sc + 8] = bv1;
        __syncthreads();
        mfma_step_s(As, Bs, wr, wc, quad, l16, accR);
        gA += 64; gB += 64;
    }
    const int slice = blockIdx.x * 2 + wc;
#pragma unroll
    for (int mi = 0; mi < 2; ++mi)
#pragma unroll
        for (int r = 0; r < 4; ++r) {
            const int gr = m0 + wr * 32 + mi * 16 + quad * 4 + r;
            float s = 0.f;
#pragma unroll
            for (int ni = 0; ni < 2; ++ni) {
                const int gc = n0 + wc * 32 + ni * 16 + l16;
                const size_t idx = (size_t)gr * DD + gc;
                const float v = accR[mi][ni][r];
                outF[idx] = v;
                s += v * nodeF[idx];
            }
            s += __shfl_xor(s, 1, 64);
            s += __shfl_xor(s, 2, 64);
            s += __shfl_xor(s, 4, 64);
            s += __shfl_xor(s, 8, 64);
            if (l16 == 0) pOut[(size_t)slice * NN + gr] = s;
        }
}

// ---------------- final: val @ theta_w^T + b, relu -> d_out (+ fused loss in block 0) ----------------
__global__ __launch_bounds__(256) void k_final(const float* __restrict__ spaF, const float* __restrict__ tmpF,
                                               const float* __restrict__ pSpa, const float* __restrict__ pTmp,
                                               const __bf16* __restrict__ thetaBf, const float* __restrict__ thetaB,
                                               const float* __restrict__ pAbs2, const float* __restrict__ pSq2,
                                               const float* __restrict__ pDiff,
                                               float* __restrict__ out) {
    const int n0 = blockIdx.x * 64, m0 = blockIdx.y * 64;
    __shared__ __bf16 As[64][72], Bs[64][72];
    f32x4 accR[2][2];
#pragma unroll
    for (int i = 0; i < 2; ++i)
#pragma unroll
        for (int j = 0; j < 2; ++j) accR[i][j] = (f32x4)0.f;
    const int t = threadIdx.x, w = t >> 6, lane = t & 63, quad = lane >> 4, l16 = lane & 15;
    const int wr = w >> 1, wc = w & 1;
    const int sr = t >> 2, sc = (t & 3) * 16;
    const int row = m0 + sr;
    float sa = 0.f, ta = 0.f;
#pragma unroll
    for (int j = 0; j < 8; ++j) {
        sa += pSpa[(size_t)j * NN + row];
        ta += pTmp[(size_t)j * NN + row];
    }
    sa *= 0.0625f; ta *= 0.0625f;   // 1/sqrt(256)
    const float* gS = spaF + (size_t)row * DD + sc;
    const float* gT = tmpF + (size_t)row * DD + sc;
    const __bf16* gB = thetaBf + (size_t)(n0 + sr) * DD + sc;
    for (int kt = 0; kt < DD / 64; ++kt) {
        __bf16 tmp[16];
#pragma unroll
        for (int e4 = 0; e4 < 4; ++e4) {
            float4 vs = ((const float4*)gS)[e4];
            float4 vt = ((const float4*)gT)[e4];
            tmp[e4 * 4 + 0] = (__bf16)(sa * vs.x + ta * vt.x);
            tmp[e4 * 4 + 1] = (__bf16)(sa * vs.y + ta * vt.y);
            tmp[e4 * 4 + 2] = (__bf16)(sa * vs.z + ta * vt.z);
            tmp[e4 * 4 + 3] = (__bf16)(sa * vs.w + ta * vt.w);
        }
        uint4 bv0 = *(const uint4*)(gB);
        uint4 bv1 = *(const uint4*)(gB + 8);
        __syncthreads();
        *(uint4*)&As[sr][sc] = *(uint4*)&tmp[0]; *(uint4*)&As[sr][sc + 8] = *(uint4*)&tmp[8];
        *(uint4*)&Bs[sr][sc] = bv0; *(uint4*)&Bs[sr][sc + 8] = bv1;
        __syncthreads();
        mfma_step_s(As, Bs, wr, wc, quad, l16, accR);
        gS += 64; gT += 64; gB += 64;
    }
#pragma unroll
    for (int mi = 0; mi < 2; ++mi)
#pragma unroll
        for (int ni = 0; ni < 2; ++ni)
#pragma unroll
            for (int r = 0; r < 4; ++r) {
                int gr = m0 + wr * 32 + mi * 16 + quad * 4 + r;
                int gc = n0 + wc * 32 + ni * 16 + l16;
                float v = accR[mi][ni][r] + thetaB[gc];
                out[(size_t)gr * DD + gc] = fmaxf(v, 0.f);
            }
    // ---- fused loss (one block) ----
    if (blockIdx.x == 0 && blockIdx.y == 0) {
        float aT = 0.f, qT = 0.f, aS = 0.f, qS = 0.f;
        if (t < 64) { aT = pAbs2[t]; qT = pSq2[t]; aS = pAbs2[64 + t]; qS = pSq2[64 + t]; }
        float dT = pDiff[t], dS = pDiff[256 + t];
        aT = wave_red(aT); qT = wave_red(qT); aS = wave_red(aS); qS = wave_red(qS);
        dT = wave_red(dT); dS = wave_red(dS);
        float (*red)[4] = (float (*)[4])As;
        if (lane == 0) { red[0][w] = aT; red[1][w] = qT; red[2][w] = aS; red[3][w] = qS; red[4][w] = dT; red[5][w] = dS; }
        __syncthreads();
        if (t == 0) {
            float s[6];
#pragma unroll
            for (int k = 0; k < 6; ++k) s[k] = red[k][0] + red[k][1] + red[k][2] + red[k][3];
            float l = s[0] + 0.001f * sqrtf(s[1]) + 0.2f * sqrtf(s[4])    // temporal
                    + s[2] + 0.001f * sqrtf(s[3]) + 0.2f * sqrtf(s[5]);   // spatial
            out[(size_t)NN * DD] = l;
        }
    }
}

extern "C" void kernel_launch(void* const* d_in, const int* in_sizes, int n_in,
                              void* d_out, int out_size, void* d_ws, size_t ws_size,
                              hipStream_t stream) {
    (void)in_sizes; (void)n_in; (void)out_size; (void)ws_size;
    const float* cur      = (const float*)d_in[0];
    const float* pre      = (const float*)d_in[1];
    const float* r_proj_s = (const float*)d_in[2];
    const float* inc_s    = (const float*)d_in[3];
    const float* r_proj_t = (const float*)d_in[4];
    const float* inc_t    = (const float*)d_in[5];
    const float* node_pj  = (const float*)d_in[6];
    const float* spa_pj   = (const float*)d_in[7];
    const float* tmp_pj   = (const float*)d_in[8];
    const float* theta_w  = (const float*)d_in[9];
    const float* theta_b  = (const float*)d_in[10];
    float* out = (float*)d_out;

    char* p = (char*)d_ws;
    auto alloc = [&](size_t bytes) -> void* {
        void* r = (void*)p;
        p += (bytes + 255) & ~(size_t)255;
        return r;
    };
    __bf16* cur_bf  = (__bf16*)alloc((size_t)NN * DD * 2);
    __bf16* curT    = (__bf16*)alloc((size_t)NN * DD * 2);
    __bf16* preT    = (__bf16*)alloc((size_t)NN * DD * 2);
    __bf16* pTs     = (__bf16*)alloc((size_t)DD * DD * 2);
    __bf16* pTt     = (__bf16*)alloc((size_t)DD * DD * 2);
    __bf16* pTn     = (__bf16*)alloc((size_t)DD * DD * 2);
    __bf16* pTspa   = (__bf16*)alloc((size_t)DD * DD * 2);
    __bf16* pTtmp   = (__bf16*)alloc((size_t)DD * DD * 2);
    __bf16* thetaBf = (__bf16*)alloc((size_t)DD * DD * 2);
    __bf16* embS    = (__bf16*)alloc((size_t)NN * DD * 2);
    __bf16* embT    = (__bf16*)alloc((size_t)NN * DD * 2);
    float* negMs    = (float*)alloc((size_t)NN * DD * 4);
    float* negMt    = (float*)alloc((size_t)NN * DD * 4);
    float* nodeFea  = (float*)alloc((size_t)NN * DD * 4);
    float* spaF     = (float*)alloc((size_t)NN * DD * 4);
    float* tmpF     = (float*)alloc((size_t)NN * DD * 4);
    float* pSpa     = (float*)alloc((size_t)8 * NN * 4);
    float* pTmp     = (float*)alloc((size_t)8 * NN * 4);
    float* pAbs2    = (float*)alloc(128 * 4);
    float* pSq2     = (float*)alloc(128 * 4);
    float* pDiff    = (float*)alloc(512 * 4);

    k_pre<<<2048, 256, 0, stream>>>(cur, pre, r_proj_s, r_proj_t, node_pj, spa_pj, tmp_pj, theta_w,
                                    cur_bf, curT, preT, pTs, pTt, pTn, pTspa, pTtmp, thetaBf);
    k_small3<<<dim3(4, 64, 3), 256, 0, stream>>>(cur_bf, pTs, pTt, pTn, negMs, negMt, nodeFea);
    k_big<<<dim3(4, 64, 2), 256, 0, stream>>>(inc_t, inc_s, preT, curT, negMt, negMs, cur,
                                              embT, embS, pDiff, pAbs2, pSq2);
    k_fea<<<dim3(4, 64, 2), 256, 0, stream>>>(embS, embT, pTspa, pTtmp, nodeFea,
                                              spaF, tmpF, pSpa, pTmp);
    k_final<<<dim3(4, 64), 256, 0, stream>>>(spaF, tmpF, pSpa, pTmp, thetaBf, theta_b,
                                             pAbs2, pSq2, pDiff, out);
}

// Round 6
// 249.205 us; speedup vs baseline: 2.0360x; 1.0515x over previous
//
#include <hip/hip_runtime.h>
#include <hip/hip_bf16.h>
#include <math.h>

#define NN 4096
#define DD 256

typedef __bf16 bf16x8 __attribute__((ext_vector_type(8)));
typedef short  short8 __attribute__((ext_vector_type(8)));
typedef float  f32x4  __attribute__((ext_vector_type(4)));
typedef float  f32x16 __attribute__((ext_vector_type(16)));

typedef __attribute__((address_space(1))) const void gv_t;
typedef __attribute__((address_space(3))) void lv_t;
#define GLD16(gp, lp) __builtin_amdgcn_global_load_lds((gv_t*)(gp), (lv_t*)(lp), 16, 0, 0)

#define MFMA16(a, b, c) __builtin_amdgcn_mfma_f32_16x16x32_bf16((a), (b), (c), 0, 0, 0)
#define MFMA32(a, b, c) __builtin_amdgcn_mfma_f32_32x32x16_bf16((a), (b), (c), 0, 0, 0)

__device__ inline bf16x8 brelu(bf16x8 a) {
    short8 s = __builtin_bit_cast(short8, a);
    s = s & ~(s >> 15);            // negative (sign bit set) -> 0, else keep
    return __builtin_bit_cast(bf16x8, s);
}

__device__ inline float wave_red(float v) {
#pragma unroll
    for (int o = 32; o > 0; o >>= 1) v += __shfl_down(v, o, 64);
    return v;
}

__device__ inline unsigned short bfbits(float f) {
    return __builtin_bit_cast(unsigned short, (__bf16)f);
}

__device__ inline void syncb() {
    asm volatile("s_waitcnt lgkmcnt(0)" ::: "memory");
    __builtin_amdgcn_s_barrier();
}

// store/load one 32x32 f32 fragment (16 regs/lane) to a 4KB LDS slot, bank-balanced.
__device__ inline void store16(float* base, const f32x16& v, int lane) {
#pragma unroll
    for (int r4 = 0; r4 < 4; ++r4) {
        f32x4 c = {v[4 * r4], v[4 * r4 + 1], v[4 * r4 + 2], v[4 * r4 + 3]};
        ((f32x4*)base)[r4 * 64 + lane] = c;
    }
}
__device__ inline void add16(f32x16& v, const float* base, int lane) {
#pragma unroll
    for (int r4 = 0; r4 < 4; ++r4) {
        f32x4 c = ((const f32x4*)base)[r4 * 64 + lane];
        v[4 * r4] += c[0]; v[4 * r4 + 1] += c[1]; v[4 * r4 + 2] += c[2]; v[4 * r4 + 3] += c[3];
    }
}

// cross-wave K-split reduction: wave W ends owning quadrant (mi=W>>1, ni=W&1).
template <int W>
__device__ inline void red_owner(f32x16 (&aR)[2][2], f32x16 (&aL)[2][2],
                                 float* scr, int lane, f32x16& oR, f32x16& oL) {
    constexpr int o1 = W ^ 1, o2 = W ^ 2, o3 = W ^ 3;
    store16(scr + W * 1024,       aR[o1 >> 1][o1 & 1], lane);
    store16(scr + (4 + W) * 1024, aR[o2 >> 1][o2 & 1], lane);
    syncb();
    oR = aR[W >> 1][W & 1];
    add16(oR, scr + o1 * 1024, lane);
    add16(oR, scr + (4 + o2) * 1024, lane);
    syncb();
    store16(scr + W * 1024, aR[o3 >> 1][o3 & 1], lane);
    syncb();
    add16(oR, scr + o3 * 1024, lane);
    syncb();
    store16(scr + W * 1024,       aL[o1 >> 1][o1 & 1], lane);
    store16(scr + (4 + W) * 1024, aL[o2 >> 1][o2 & 1], lane);
    syncb();
    oL = aL[W >> 1][W & 1];
    add16(oL, scr + o1 * 1024, lane);
    add16(oL, scr + (4 + o2) * 1024, lane);
    syncb();
    store16(scr + W * 1024, aL[o3 >> 1][o3 & 1], lane);
    syncb();
    add16(oL, scr + o3 * 1024, lane);
}

// ---------------- preprocessing: prep transpose + proj matrices ----------------
__global__ __launch_bounds__(256) void k_pre(
    const float* __restrict__ cur, const float* __restrict__ pre,
    const float* __restrict__ r_proj_s, const float* __restrict__ r_proj_t,
    const float* __restrict__ node_pj, const float* __restrict__ spa_pj,
    const float* __restrict__ tmp_pj, const float* __restrict__ theta_w,
    __bf16* __restrict__ cur_bf, __bf16* __restrict__ curT, __bf16* __restrict__ preT,
    __bf16* __restrict__ pTs, __bf16* __restrict__ pTt, __bf16* __restrict__ pTn,
    __bf16* __restrict__ pTspa, __bf16* __restrict__ pTtmp, __bf16* __restrict__ thetaBf) {
    __shared__ unsigned short tile[64][72];
    const int b = blockIdx.x, t = threadIdx.x;
    if (b < 512) {
        const int x = b & 63, y = (b >> 6) & 3, z = b >> 8;
        const int i0 = x * 64, d0 = y * 64;
        const float* src = z ? pre : cur;
        __bf16* dstT = z ? preT : curT;
        const int r = t >> 2, c4 = (t & 3) * 16;
        const float* srow = src + (size_t)(i0 + r) * DD + d0 + c4;
        alignas(16) unsigned short loc[16];
#pragma unroll
        for (int e = 0; e < 4; ++e) {
            float4 v = ((const float4*)srow)[e];
            loc[e * 4 + 0] = bfbits(v.x);
            loc[e * 4 + 1] = bfbits(v.y);
            loc[e * 4 + 2] = bfbits(v.z);
            loc[e * 4 + 3] = bfbits(v.w);
        }
#pragma unroll
        for (int e = 0; e < 16; ++e) tile[r][c4 + e] = loc[e];
        if (z == 0) {
            __bf16* drow = cur_bf + (size_t)(i0 + r) * DD + d0 + c4;
            *(uint4*)drow = *(uint4*)&loc[0];
            *(uint4*)(drow + 8) = *(uint4*)&loc[8];
        }
        __syncthreads();
        alignas(16) unsigned short o[16];
#pragma unroll
        for (int e = 0; e < 16; ++e) o[e] = tile[c4 + e][r];
        __bf16* trow = dstT + (size_t)(d0 + r) * NN + i0 + c4;
        *(uint4*)trow = *(uint4*)&o[0];
        *(uint4*)(trow + 8) = *(uint4*)&o[8];
    } else {
        const int bb = b - 512;
        const int id = bb >> 8, r = bb & 255;
        const float* src = id == 0 ? r_proj_s : id == 1 ? r_proj_t : id == 2 ? node_pj
                         : id == 3 ? spa_pj : id == 4 ? tmp_pj : theta_w;
        __bf16* dst = id == 0 ? pTs : id == 1 ? pTt : id == 2 ? pTn
                    : id == 3 ? pTspa : id == 4 ? pTtmp : thetaBf;
        float v = src[r * DD + t];
        if (id < 5) dst[t * DD + r] = (__bf16)v;
        else        dst[r * DD + t] = (__bf16)v;
    }
}

// ---------------- streaming conv: inc_t / inc_s -> bf16 (zero-diag scatter via window repair) ----------------
// 2048 blocks x 4 rows. No LDS data staging; fully coalesced dwordx4 reads + ushort4 writes.
__global__ __launch_bounds__(256) void k_conv(const float* __restrict__ inc_t,
                                              const float* __restrict__ inc_s,
                                              __bf16* __restrict__ Mt, __bf16* __restrict__ Ms,
                                              float* __restrict__ rsT, float* __restrict__ rsS,
                                              float* __restrict__ pAbsT, float* __restrict__ pSqT,
                                              float* __restrict__ pAbsS, float* __restrict__ pSqS) {
    const int b = blockIdx.x, t = threadIdx.x;
    const int zs = (b >= 1024);
    const int r0 = (zs ? b - 1024 : b) * 4;
    __shared__ float red[3][4];
    const int w = t >> 6, lane = t & 63;
    for (int rr = 0; rr < 4; ++rr) {
        const int i = r0 + rr;
        float rs = 0.f, as = 0.f, qs = 0.f;
        if (!zs) {
            const float4* src = (const float4*)(inc_t + (size_t)i * NN);
            ushort4* dst = (ushort4*)(Mt + (size_t)i * NN);
            float4 v[4];
#pragma unroll
            for (int e = 0; e < 4; ++e) v[e] = src[t + 256 * e];
#pragma unroll
            for (int e = 0; e < 4; ++e) {
                float x[4] = {v[e].x, v[e].y, v[e].z, v[e].w};
                unsigned short o[4];
#pragma unroll
                for (int j = 0; j < 4; ++j) {
                    float fv = x[j];
                    as += fabsf(fv); qs += fv * fv; rs += fmaxf(fv, 0.f);
                    o[j] = bfbits(fv);
                }
                dst[t + 256 * e] = make_ushort4(o[0], o[1], o[2], o[3]);
            }
        } else {
            // zero-diag scatter: dest[k] = k<i ? src[k] : (k==i ? 0 : src[k-1])
            const float* srow = inc_s + (size_t)i * (NN - 1);
            ushort4* dst = (ushort4*)(Ms + (size_t)i * NN);
            float lx[16];
            int dv[4];
#pragma unroll
            for (int e = 0; e < 4; ++e) {
                const int c0 = 4 * (t + 256 * e);
                const int d = (c0 > i) || (c0 == NN - 4);   // tail clamp keeps window in-bounds
                dv[e] = d;
                __builtin_memcpy(&lx[4 * e], srow + (c0 - d), 16);
            }
#pragma unroll
            for (int e = 0; e < 4; ++e) {
                const int c0 = 4 * (t + 256 * e), d = dv[e];
                unsigned short o[4];
#pragma unroll
                for (int j = 0; j < 4; ++j) {
                    const int k = c0 + j;
                    float alt = d ? ((j < 3) ? lx[4 * e + j + 1] : 0.f) : lx[4 * e + j];     // src[k]
                    float agt = d ? lx[4 * e + j] : ((j > 0) ? lx[4 * e + j - 1] : 0.f);     // src[k-1]
                    float fv = (k < i) ? alt : ((k == i) ? 0.f : agt);
                    as += fabsf(fv); qs += fv * fv; rs += fmaxf(fv, 0.f);
                    o[j] = bfbits(fv);
                }
                dst[t + 256 * e] = make_ushort4(o[0], o[1], o[2], o[3]);
            }
        }
        rs = wave_red(rs); as = wave_red(as); qs = wave_red(qs);
        if (lane == 0) { red[0][w] = rs; red[1][w] = as; red[2][w] = qs; }
        __syncthreads();
        if (t == 0) {
            float r0v = red[0][0] + red[0][1] + red[0][2] + red[0][3];
            float r1v = red[1][0] + red[1][1] + red[1][2] + red[1][3];
            float r2v = red[2][0] + red[2][1] + red[2][2] + red[2][3];
            if (!zs) { rsT[i] = r0v; pAbsT[i] = r1v; pSqT[i] = r2v; }
            else     { rsS[i] = r0v; pAbsS[i] = r1v; pSqS[i] = r2v; }
        }
        __syncthreads();
    }
}

// ---------------- big dual GEMM, K-split across waves (round-3 structure, validated) ----------------
__global__ __launch_bounds__(256, 2) void k_big(const __bf16* __restrict__ Mt, const __bf16* __restrict__ Ms,
                                                const __bf16* __restrict__ preT, const __bf16* __restrict__ curT,
                                                const float* __restrict__ negMt, const float* __restrict__ negMs,
                                                const float* __restrict__ cur,
                                                const float* __restrict__ rsT, const float* __restrict__ rsS,
                                                __bf16* __restrict__ embT, __bf16* __restrict__ embS,
                                                float* __restrict__ pDiff) {
    const int flat = blockIdx.x + 4 * (blockIdx.y + 64 * blockIdx.z);
    const int swz = (flat & 7) * 64 + (flat >> 3);
    const int bx = swz & 3, by = (swz >> 2) & 63, z = swz >> 8;
    const __bf16* A  = z ? Ms : Mt;
    const __bf16* BT = z ? curT : preT;
    const float* negM = z ? negMs : negMt;
    const float* rs   = z ? rsS : rsT;
    __bf16* emb       = z ? embS : embT;
    const int n0 = bx * 64, m0 = by * 64;
    __shared__ __align__(16) char smraw[65536];
    __bf16 (*sm)[2][64][64] = (__bf16 (*)[2][64][64])smraw;   // [buf][A/B][row][col]
    float* scr = (float*)smraw;                               // reduce scratch (overlays bufs 0,1)
    f32x16 accR[2][2], accL[2][2];
#pragma unroll
    for (int i = 0; i < 2; ++i)
#pragma unroll
        for (int j = 0; j < 2; ++j) { accR[i][j] = (f32x16)0.f; accL[i][j] = (f32x16)0.f; }
    const int t = threadIdx.x, w = t >> 6, lane = t & 63;
    const int lr = lane >> 3, lc = lane & 7;
    const int q0 = 2 * w, q1 = q0 + 1;
    const int csw = (lc ^ lr) * 8;
    const __bf16* gA0 = A + (size_t)(m0 + 8 * q0 + lr) * NN + csw;
    const __bf16* gA1 = A + (size_t)(m0 + 8 * q1 + lr) * NN + csw;
    const __bf16* gB0 = BT + (size_t)(n0 + 8 * q0 + lr) * NN + csw;
    const __bf16* gB1 = BT + (size_t)(n0 + 8 * q1 + lr) * NN + csw;
    auto stage = [&](int b, int tk) {
        const int ko = tk * 64;
        GLD16(gA0 + ko, &sm[b][0][8 * q0][0]);
        GLD16(gA1 + ko, &sm[b][0][8 * q1][0]);
        GLD16(gB0 + ko, &sm[b][1][8 * q0][0]);
        GLD16(gB1 + ko, &sm[b][1][8 * q1][0]);
    };
    stage(0, 0); stage(1, 1); stage(2, 2); stage(3, 3);
    asm volatile("s_waitcnt vmcnt(8)" ::: "memory");          // tiles 0,1 landed
    __builtin_amdgcn_s_barrier();
    __builtin_amdgcn_sched_barrier(0);
    const int fr = lane & 31, h = lane >> 5;
    const int swc = ((2 * w + h) ^ (fr & 7)) * 8;             // swizzled 16B chunk (constant)
    for (int it = 0; it < 32; ++it) {
        const int b0 = (2 * it) & 3, b1 = b0 + 1;
        bf16x8 a[2][2], bb[2][2];
#pragma unroll
        for (int mi = 0; mi < 2; ++mi) {
            a[0][mi]  = *(const bf16x8*)&sm[b0][0][mi * 32 + fr][swc];
            a[1][mi]  = *(const bf16x8*)&sm[b1][0][mi * 32 + fr][swc];
            bb[0][mi] = *(const bf16x8*)&sm[b0][1][mi * 32 + fr][swc];
            bb[1][mi] = *(const bf16x8*)&sm[b1][1][mi * 32 + fr][swc];
        }
        asm volatile("s_waitcnt lgkmcnt(0)" ::: "memory");    // fragments in regs
        __builtin_amdgcn_sched_barrier(0);
        __builtin_amdgcn_s_barrier();                         // bufs b0,b1 free
        __builtin_amdgcn_sched_barrier(0);
        if (it < 30) { stage(b0, 2 * it + 4); stage(b1, 2 * it + 5); }
        __builtin_amdgcn_sched_barrier(0);
        __builtin_amdgcn_s_setprio(1);
#pragma unroll
        for (int u = 0; u < 2; ++u)
#pragma unroll
            for (int mi = 0; mi < 2; ++mi) {
                bf16x8 ar = brelu(a[u][mi]);
#pragma unroll
                for (int ni = 0; ni < 2; ++ni) {
                    accR[mi][ni] = MFMA32(a[u][mi], bb[u][ni], accR[mi][ni]);
                    accL[mi][ni] = MFMA32(ar,       bb[u][ni], accL[mi][ni]);
                }
            }
        __builtin_amdgcn_s_setprio(0);
        if (it < 31) {
            if (it < 30) asm volatile("s_waitcnt vmcnt(8)" ::: "memory");   // next pair landed
            else         asm volatile("s_waitcnt vmcnt(0)" ::: "memory");
            __builtin_amdgcn_s_barrier();
            __builtin_amdgcn_sched_barrier(0);
        }
    }
    // cross-wave reduce: wave w owns quadrant (w>>1, w&1)
    f32x16 oR, oL;
    if      (w == 0) red_owner<0>(accR, accL, scr, lane, oR, oL);
    else if (w == 1) red_owner<1>(accR, accL, scr, lane, oR, oL);
    else if (w == 2) red_owner<2>(accR, accL, scr, lane, oR, oL);
    else             red_owner<3>(accR, accL, scr, lane, oR, oL);
    const int mi = w >> 1, ni = w & 1;
    float sumd = 0.f;
#pragma unroll
    for (int reg = 0; reg < 16; ++reg) {
        const int rr = (reg & 3) + 8 * (reg >> 2) + 4 * h;
        const int gr = m0 + mi * 32 + rr;
        const int gc = n0 + ni * 32 + fr;
        const size_t idx = (size_t)gr * DD + gc;
        float diff = oR[reg] + negM[idx];                     // recon - master
        sumd += diff * diff;
        emb[idx] = (__bf16)((oL[reg] + cur[idx]) * (1.f / (rs[gr] + 1.f)));
    }
    sumd = wave_red(sumd);
    float* sredp = (float*)(smraw + 32768);                   // bufs 2,3 region (free)
    if (lane == 0) sredp[w] = sumd;
    __syncthreads();
    if (t == 0)
        pDiff[z * 256 + by * 4 + bx] = sredp[0] + sredp[1] + sredp[2] + sredp[3];
}

// ---------------- shared MFMA inner step for the small (padded-LDS) GEMMs ----------------
__device__ inline void mfma_step_s(const __bf16 (&As)[64][72], const __bf16 (&Bs)[64][72],
                                   int wr, int wc, int quad, int l16,
                                   f32x4 (&accR)[2][2]) {
#pragma unroll
    for (int ks = 0; ks < 2; ++ks) {
        const int kc = ks * 32 + quad * 8;
        bf16x8 a0 = *(const bf16x8*)&As[wr * 32 + l16][kc];
        bf16x8 a1 = *(const bf16x8*)&As[wr * 32 + 16 + l16][kc];
        bf16x8 b0 = *(const bf16x8*)&Bs[wc * 32 + l16][kc];
        bf16x8 b1 = *(const bf16x8*)&Bs[wc * 32 + 16 + l16][kc];
        accR[0][0] = MFMA16(a0, b0, accR[0][0]);
        accR[0][1] = MFMA16(a0, b1, accR[0][1]);
        accR[1][0] = MFMA16(a1, b0, accR[1][0]);
        accR[1][1] = MFMA16(a1, b1, accR[1][1]);
    }
}

// ---------------- small GEMMs: -master_s, -master_t, node_fea ----------------
__global__ __launch_bounds__(256) void k_small3(const __bf16* __restrict__ cur_bf,
                                                const __bf16* __restrict__ pTs, const __bf16* __restrict__ pTt,
                                                const __bf16* __restrict__ pTn,
                                                float* __restrict__ negMs, float* __restrict__ negMt,
                                                float* __restrict__ nodeFea) {
    const int z = blockIdx.z;
    const __bf16* BT = z == 0 ? pTs : (z == 1 ? pTt : pTn);
    const int n0 = blockIdx.x * 64, m0 = blockIdx.y * 64;
    __shared__ __bf16 As[64][72], Bs[64][72];
    f32x4 accR[2][2];
#pragma unroll
    for (int i = 0; i < 2; ++i)
#pragma unroll
        for (int j = 0; j < 2; ++j) accR[i][j] = (f32x4)0.f;
    const int t = threadIdx.x, w = t >> 6, lane = t & 63, quad = lane >> 4, l16 = lane & 15;
    const int wr = w >> 1, wc = w & 1;
    const int sr = t >> 2, sc = (t & 3) * 16;
    const __bf16* gA = cur_bf + (size_t)(m0 + sr) * DD + sc;
    const __bf16* gB = BT + (size_t)(n0 + sr) * DD + sc;
    for (int kt = 0; kt < DD / 64; ++kt) {
        uint4 av0 = *(const uint4*)(gA);
        uint4 av1 = *(const uint4*)(gA + 8);
        uint4 bv0 = *(const uint4*)(gB);
        uint4 bv1 = *(const uint4*)(gB + 8);
        __syncthreads();
        *(uint4*)&As[sr][sc] = av0; *(uint4*)&As[sr][sc + 8] = av1;
        *(uint4*)&Bs[sr][sc] = bv0; *(uint4*)&Bs[sr][sc + 8] = bv1;
        __syncthreads();
        mfma_step_s(As, Bs, wr, wc, quad, l16, accR);
        gA += 64; gB += 64;
    }
#pragma unroll
    for (int mi = 0; mi < 2; ++mi)
#pragma unroll
        for (int ni = 0; ni < 2; ++ni)
#pragma unroll
            for (int r = 0; r < 4; ++r) {
                int gr = m0 + wr * 32 + mi * 16 + quad * 4 + r;
                int gc = n0 + wc * 32 + ni * 16 + l16;
                size_t idx = (size_t)gr * DD + gc;
                float v = accR[mi][ni][r];
                if (z == 0) negMs[idx] = -v;
                else if (z == 1) negMt[idx] = -v;
                else nodeFea[idx] = v;
            }
}

// ---------------- edge-feature projections + fused attention partial dots ----------------
__global__ __launch_bounds__(256) void k_fea(const __bf16* __restrict__ embS, const __bf16* __restrict__ embT,
                                             const __bf16* __restrict__ pTspa, const __bf16* __restrict__ pTtmp,
                                             const float* __restrict__ nodeF,
                                             float* __restrict__ spaF, float* __restrict__ tmpF,
                                             float* __restrict__ pSpa, float* __restrict__ pTmp) {
    const int z = blockIdx.z;
    const __bf16* Ae = z ? embT : embS;
    const __bf16* BT = z ? pTtmp : pTspa;
    float* outF = z ? tmpF : spaF;
    float* pOut = z ? pTmp : pSpa;
    const int n0 = blockIdx.x * 64, m0 = blockIdx.y * 64;
    __shared__ __bf16 As[64][72], Bs[64][72];
    f32x4 accR[2][2];
#pragma unroll
    for (int i = 0; i < 2; ++i)
#pragma unroll
        for (int j = 0; j < 2; ++j) accR[i][j] = (f32x4)0.f;
    const int t = threadIdx.x, w = t >> 6, lane = t & 63, quad = lane >> 4, l16 = lane & 15;
    const int wr = w >> 1, wc = w & 1;
    const int sr = t >> 2, sc = (t & 3) * 16;
    const __bf16* gA = Ae + (size_t)(m0 + sr) * DD + sc;
    const __bf16* gB = BT + (size_t)(n0 + sr) * DD + sc;
    for (int kt = 0; kt < DD / 64; ++kt) {
        uint4 av0 = *(const uint4*)(gA);
        uint4 av1 = *(const uint4*)(gA + 8);
        uint4 bv0 = *(const uint4*)(gB);
        uint4 bv1 = *(const uint4*)(gB + 8);
        __syncthreads();
        *(uint4*)&As[sr][sc] = av0; *(uint4*)&As[sr][sc + 8] = av1;
        *(uint4*)&Bs[sr][sc] = bv0; *(uint4*)&Bs[sr][sc + 8] = bv1;
        __syncthreads();
        mfma_step_s(As, Bs, wr, wc, quad, l16, accR);
        gA += 64; gB += 64;
    }
    const int slice = blockIdx.x * 2 + wc;
#pragma unroll
    for (int mi = 0; mi < 2; ++mi)
#pragma unroll
        for (int r = 0; r < 4; ++r) {
            const int gr = m0 + wr * 32 + mi * 16 + quad * 4 + r;
            float s = 0.f;
#pragma unroll
            for (int ni = 0; ni < 2; ++ni) {
                const int gc = n0 + wc * 32 + ni * 16 + l16;
                const size_t idx = (size_t)gr * DD + gc;
                const float v = accR[mi][ni][r];
                outF[idx] = v;
                s += v * nodeF[idx];
            }
            s += __shfl_xor(s, 1, 64);
            s += __shfl_xor(s, 2, 64);
            s += __shfl_xor(s, 4, 64);
            s += __shfl_xor(s, 8, 64);
            if (l16 == 0) pOut[(size_t)slice * NN + gr] = s;
        }
}

// ---------------- final: val @ theta_w^T + b, relu -> d_out (+ fused loss in block 0) ----------------
__global__ __launch_bounds__(256) void k_final(const float* __restrict__ spaF, const float* __restrict__ tmpF,
                                               const float* __restrict__ pSpa, const float* __restrict__ pTmp,
                                               const __bf16* __restrict__ thetaBf, const float* __restrict__ thetaB,
                                               const float* __restrict__ pAbsT, const float* __restrict__ pSqT,
                                               const float* __restrict__ pAbsS, const float* __restrict__ pSqS,
                                               const float* __restrict__ pDiff,
                                               float* __restrict__ out) {
    const int n0 = blockIdx.x * 64, m0 = blockIdx.y * 64;
    __shared__ __bf16 As[64][72], Bs[64][72];
    f32x4 accR[2][2];
#pragma unroll
    for (int i = 0; i < 2; ++i)
#pragma unroll
        for (int j = 0; j < 2; ++j) accR[i][j] = (f32x4)0.f;
    const int t = threadIdx.x, w = t >> 6, lane = t & 63, quad = lane >> 4, l16 = lane & 15;
    const int wr = w >> 1, wc = w & 1;
    const int sr = t >> 2, sc = (t & 3) * 16;
    const int row = m0 + sr;
    float sa = 0.f, ta = 0.f;
#pragma unroll
    for (int j = 0; j < 8; ++j) {
        sa += pSpa[(size_t)j * NN + row];
        ta += pTmp[(size_t)j * NN + row];
    }
    sa *= 0.0625f; ta *= 0.0625f;   // 1/sqrt(256)
    const float* gS = spaF + (size_t)row * DD + sc;
    const float* gT = tmpF + (size_t)row * DD + sc;
    const __bf16* gB = thetaBf + (size_t)(n0 + sr) * DD + sc;
    for (int kt = 0; kt < DD / 64; ++kt) {
        __bf16 tmp[16];
#pragma unroll
        for (int e4 = 0; e4 < 4; ++e4) {
            float4 vs = ((const float4*)gS)[e4];
            float4 vt = ((const float4*)gT)[e4];
            tmp[e4 * 4 + 0] = (__bf16)(sa * vs.x + ta * vt.x);
            tmp[e4 * 4 + 1] = (__bf16)(sa * vs.y + ta * vt.y);
            tmp[e4 * 4 + 2] = (__bf16)(sa * vs.z + ta * vt.z);
            tmp[e4 * 4 + 3] = (__bf16)(sa * vs.w + ta * vt.w);
        }
        uint4 bv0 = *(const uint4*)(gB);
        uint4 bv1 = *(const uint4*)(gB + 8);
        __syncthreads();
        *(uint4*)&As[sr][sc] = *(uint4*)&tmp[0]; *(uint4*)&As[sr][sc + 8] = *(uint4*)&tmp[8];
        *(uint4*)&Bs[sr][sc] = bv0; *(uint4*)&Bs[sr][sc + 8] = bv1;
        __syncthreads();
        mfma_step_s(As, Bs, wr, wc, quad, l16, accR);
        gS += 64; gT += 64; gB += 64;
    }
#pragma unroll
    for (int mi = 0; mi < 2; ++mi)
#pragma unroll
        for (int ni = 0; ni < 2; ++ni)
#pragma unroll
            for (int r = 0; r < 4; ++r) {
                int gr = m0 + wr * 32 + mi * 16 + quad * 4 + r;
                int gc = n0 + wc * 32 + ni * 16 + l16;
                float v = accR[mi][ni][r] + thetaB[gc];
                out[(size_t)gr * DD + gc] = fmaxf(v, 0.f);
            }
    // ---- fused loss (one block) ----
    if (blockIdx.x == 0 && blockIdx.y == 0) {
        float aT = 0.f, qT = 0.f, aS = 0.f, qS = 0.f;
#pragma unroll
        for (int j = 0; j < 16; ++j) {
            const int i = t + 256 * j;
            aT += pAbsT[i]; qT += pSqT[i]; aS += pAbsS[i]; qS += pSqS[i];
        }
        float dT = pDiff[t], dS = pDiff[256 + t];
        aT = wave_red(aT); qT = wave_red(qT); aS = wave_red(aS); qS = wave_red(qS);
        dT = wave_red(dT); dS = wave_red(dS);
        float (*red)[4] = (float (*)[4])As;
        if (lane == 0) { red[0][w] = aT; red[1][w] = qT; red[2][w] = aS; red[3][w] = qS; red[4][w] = dT; red[5][w] = dS; }
        __syncthreads();
        if (t == 0) {
            float s[6];
#pragma unroll
            for (int k = 0; k < 6; ++k) s[k] = red[k][0] + red[k][1] + red[k][2] + red[k][3];
            float l = s[0] + 0.001f * sqrtf(s[1]) + 0.2f * sqrtf(s[4])    // temporal
                    + s[2] + 0.001f * sqrtf(s[3]) + 0.2f * sqrtf(s[5]);   // spatial
            out[(size_t)NN * DD] = l;
        }
    }
}

extern "C" void kernel_launch(void* const* d_in, const int* in_sizes, int n_in,
                              void* d_out, int out_size, void* d_ws, size_t ws_size,
                              hipStream_t stream) {
    (void)in_sizes; (void)n_in; (void)out_size; (void)ws_size;
    const float* cur      = (const float*)d_in[0];
    const float* pre      = (const float*)d_in[1];
    const float* r_proj_s = (const float*)d_in[2];
    const float* inc_s    = (const float*)d_in[3];
    const float* r_proj_t = (const float*)d_in[4];
    const float* inc_t    = (const float*)d_in[5];
    const float* node_pj  = (const float*)d_in[6];
    const float* spa_pj   = (const float*)d_in[7];
    const float* tmp_pj   = (const float*)d_in[8];
    const float* theta_w  = (const float*)d_in[9];
    const float* theta_b  = (const float*)d_in[10];
    float* out = (float*)d_out;

    char* p = (char*)d_ws;
    auto alloc = [&](size_t bytes) -> void* {
        void* r = (void*)p;
        p += (bytes + 255) & ~(size_t)255;
        return r;
    };
    __bf16* Mt      = (__bf16*)alloc((size_t)NN * NN * 2);
    __bf16* Ms      = (__bf16*)alloc((size_t)NN * NN * 2);
    __bf16* cur_bf  = (__bf16*)alloc((size_t)NN * DD * 2);
    __bf16* curT    = (__bf16*)alloc((size_t)NN * DD * 2);
    __bf16* preT    = (__bf16*)alloc((size_t)NN * DD * 2);
    __bf16* pTs     = (__bf16*)alloc((size_t)DD * DD * 2);
    __bf16* pTt     = (__bf16*)alloc((size_t)DD * DD * 2);
    __bf16* pTn     = (__bf16*)alloc((size_t)DD * DD * 2);
    __bf16* pTspa   = (__bf16*)alloc((size_t)DD * DD * 2);
    __bf16* pTtmp   = (__bf16*)alloc((size_t)DD * DD * 2);
    __bf16* thetaBf = (__bf16*)alloc((size_t)DD * DD * 2);
    __bf16* embS    = (__bf16*)alloc((size_t)NN * DD * 2);
    __bf16* embT    = (__bf16*)alloc((size_t)NN * DD * 2);
    float* negMs    = (float*)alloc((size_t)NN * DD * 4);
    float* negMt    = (float*)alloc((size_t)NN * DD * 4);
    float* nodeFea  = (float*)alloc((size_t)NN * DD * 4);
    float* spaF     = (float*)alloc((size_t)NN * DD * 4);
    float* tmpF     = (float*)alloc((size_t)NN * DD * 4);
    float* rsS      = (float*)alloc((size_t)NN * 4);
    float* rsT      = (float*)alloc((size_t)NN * 4);
    float* pSpa     = (float*)alloc((size_t)8 * NN * 4);
    float* pTmp     = (float*)alloc((size_t)8 * NN * 4);
    float* pAbsT    = (float*)alloc((size_t)NN * 4);
    float* pSqT     = (float*)alloc((size_t)NN * 4);
    float* pAbsS    = (float*)alloc((size_t)NN * 4);
    float* pSqS     = (float*)alloc((size_t)NN * 4);
    float* pDiff    = (float*)alloc(512 * 4);

    k_pre<<<2048, 256, 0, stream>>>(cur, pre, r_proj_s, r_proj_t, node_pj, spa_pj, tmp_pj, theta_w,
                                    cur_bf, curT, preT, pTs, pTt, pTn, pTspa, pTtmp, thetaBf);
    k_conv<<<2048, 256, 0, stream>>>(inc_t, inc_s, Mt, Ms, rsT, rsS,
                                     pAbsT, pSqT, pAbsS, pSqS);
    k_small3<<<dim3(4, 64, 3), 256, 0, stream>>>(cur_bf, pTs, pTt, pTn, negMs, negMt, nodeFea);
    k_big<<<dim3(4, 64, 2), 256, 0, stream>>>(Mt, Ms, preT, curT, negMt, negMs, cur,
                                              rsT, rsS, embT, embS, pDiff);
    k_fea<<<dim3(4, 64, 2), 256, 0, stream>>>(embS, embT, pTspa, pTtmp, nodeFea,
                                              spaF, tmpF, pSpa, pTmp);
    k_final<<<dim3(4, 64), 256, 0, stream>>>(spaF, tmpF, pSpa, pTmp, thetaBf, theta_b,
                                             pAbsT, pSqT, pAbsS, pSqS, pDiff, out);
}

// Round 7
// 243.709 us; speedup vs baseline: 2.0819x; 1.0225x over previous
//
#include <hip/hip_runtime.h>
#include <hip/hip_bf16.h>
#include <math.h>

#define NN 4096
#define DD 256

typedef __bf16 bf16x8 __attribute__((ext_vector_type(8)));
typedef short  short8 __attribute__((ext_vector_type(8)));
typedef float  f32x4  __attribute__((ext_vector_type(4)));
typedef float  f32x16 __attribute__((ext_vector_type(16)));

typedef __attribute__((address_space(1))) const void gv_t;
typedef __attribute__((address_space(3))) void lv_t;
#define GLD16(gp, lp) __builtin_amdgcn_global_load_lds((gv_t*)(gp), (lv_t*)(lp), 16, 0, 0)

#define MFMA16(a, b, c) __builtin_amdgcn_mfma_f32_16x16x32_bf16((a), (b), (c), 0, 0, 0)
#define MFMA32(a, b, c) __builtin_amdgcn_mfma_f32_32x32x16_bf16((a), (b), (c), 0, 0, 0)

__device__ inline bf16x8 brelu(bf16x8 a) {
    short8 s = __builtin_bit_cast(short8, a);
    s = s & ~(s >> 15);            // negative (sign bit set) -> 0, else keep
    return __builtin_bit_cast(bf16x8, s);
}

__device__ inline float wave_red(float v) {
#pragma unroll
    for (int o = 32; o > 0; o >>= 1) v += __shfl_down(v, o, 64);
    return v;
}

__device__ inline unsigned short bfbits(float f) {
    return __builtin_bit_cast(unsigned short, (__bf16)f);
}

__device__ inline void syncb() {
    asm volatile("s_waitcnt lgkmcnt(0)" ::: "memory");
    __builtin_amdgcn_s_barrier();
}

// store/load one 32x32 f32 fragment (16 regs/lane) to a 4KB LDS slot, bank-balanced.
__device__ inline void store16(float* base, const f32x16& v, int lane) {
#pragma unroll
    for (int r4 = 0; r4 < 4; ++r4) {
        f32x4 c = {v[4 * r4], v[4 * r4 + 1], v[4 * r4 + 2], v[4 * r4 + 3]};
        ((f32x4*)base)[r4 * 64 + lane] = c;
    }
}
__device__ inline void add16(f32x16& v, const float* base, int lane) {
#pragma unroll
    for (int r4 = 0; r4 < 4; ++r4) {
        f32x4 c = ((const f32x4*)base)[r4 * 64 + lane];
        v[4 * r4] += c[0]; v[4 * r4 + 1] += c[1]; v[4 * r4 + 2] += c[2]; v[4 * r4 + 3] += c[3];
    }
}

// cross-wave K-split reduction: wave W ends owning quadrant (mi=W>>1, ni=W&1).
template <int W>
__device__ inline void red_owner(f32x16 (&aR)[2][2], f32x16 (&aL)[2][2],
                                 float* scr, int lane, f32x16& oR, f32x16& oL) {
    constexpr int o1 = W ^ 1, o2 = W ^ 2, o3 = W ^ 3;
    store16(scr + W * 1024,       aR[o1 >> 1][o1 & 1], lane);
    store16(scr + (4 + W) * 1024, aR[o2 >> 1][o2 & 1], lane);
    syncb();
    oR = aR[W >> 1][W & 1];
    add16(oR, scr + o1 * 1024, lane);
    add16(oR, scr + (4 + o2) * 1024, lane);
    syncb();
    store16(scr + W * 1024, aR[o3 >> 1][o3 & 1], lane);
    syncb();
    add16(oR, scr + o3 * 1024, lane);
    syncb();
    store16(scr + W * 1024,       aL[o1 >> 1][o1 & 1], lane);
    store16(scr + (4 + W) * 1024, aL[o2 >> 1][o2 & 1], lane);
    syncb();
    oL = aL[W >> 1][W & 1];
    add16(oL, scr + o1 * 1024, lane);
    add16(oL, scr + (4 + o2) * 1024, lane);
    syncb();
    store16(scr + W * 1024, aL[o3 >> 1][o3 & 1], lane);
    syncb();
    add16(oL, scr + o3 * 1024, lane);
}

// ---------------- merged preprocessing: conv_t | conv_s (wave-per-row) | prep | proj ----------------
// conv: one wave per row, no LDS, no barriers. Paired float4 loads -> one uint4 (8 bf16) store.
__global__ __launch_bounds__(256) void k_prec(
    const float* __restrict__ cur, const float* __restrict__ pre,
    const float* __restrict__ r_proj_s, const float* __restrict__ r_proj_t,
    const float* __restrict__ node_pj, const float* __restrict__ spa_pj,
    const float* __restrict__ tmp_pj, const float* __restrict__ theta_w,
    const float* __restrict__ inc_t, const float* __restrict__ inc_s,
    __bf16* __restrict__ cur_bf, __bf16* __restrict__ curT, __bf16* __restrict__ preT,
    __bf16* __restrict__ pTs, __bf16* __restrict__ pTt, __bf16* __restrict__ pTn,
    __bf16* __restrict__ pTspa, __bf16* __restrict__ pTtmp, __bf16* __restrict__ thetaBf,
    __bf16* __restrict__ Mt, __bf16* __restrict__ Ms,
    float* __restrict__ rsT, float* __restrict__ pAbsT, float* __restrict__ pSqT,
    float* __restrict__ rsS, float* __restrict__ pAbsS, float* __restrict__ pSqS) {
    __shared__ unsigned short tile[64][72];
    const int b = blockIdx.x, t = threadIdx.x;
    const int w = t >> 6, lane = t & 63;
    if (b < 2048) {
        // ---- conv: wave w handles one full row ----
        const int zs = (b >= 1024);
        const int i = (((zs ? b - 1024 : b) << 2) | w);
        float rs = 0.f, as = 0.f, qs = 0.f;
        if (!zs) {
            const float4* src = (const float4*)(inc_t + (size_t)i * NN);
            uint4* dst = (uint4*)(Mt + (size_t)i * NN);
#pragma unroll
            for (int e2 = 0; e2 < 8; ++e2) {
                const int g = e2 * 64 + lane;                 // uint4 chunk in [0,512)
                float4 v0 = src[2 * g], v1 = src[2 * g + 1];
                float x[8] = {v0.x, v0.y, v0.z, v0.w, v1.x, v1.y, v1.z, v1.w};
                alignas(16) unsigned short o[8];
#pragma unroll
                for (int j = 0; j < 8; ++j) {
                    float fv = x[j];
                    as += fabsf(fv); qs += fv * fv; rs += fmaxf(fv, 0.f);
                    o[j] = bfbits(fv);
                }
                dst[g] = *(uint4*)o;
            }
            if (lane == 0) { rsT[i] = wave_red(0.f), rsT[i] = rs; }   // placeholder avoided below
            rs = wave_red(rs); as = wave_red(as); qs = wave_red(qs);
            if (lane == 0) { rsT[i] = rs; pAbsT[i] = as; pSqT[i] = qs; }
        } else {
            // zero-diag scatter: dest[k] = k<i ? src[k] : (k==i ? 0 : src[k-1])
            const float* srow = inc_s + (size_t)i * (NN - 1);
            uint4* dst = (uint4*)(Ms + (size_t)i * NN);
#pragma unroll
            for (int e2 = 0; e2 < 8; ++e2) {
                const int g = e2 * 64 + lane;
                float lx[8];
                int dv[2];
#pragma unroll
                for (int h = 0; h < 2; ++h) {
                    const int c0 = 8 * g + 4 * h;
                    const int d = (c0 > i) || (c0 == NN - 4);  // tail clamp keeps window in-bounds
                    dv[h] = d;
                    __builtin_memcpy(&lx[4 * h], srow + (c0 - d), 16);
                }
                alignas(16) unsigned short o[8];
#pragma unroll
                for (int h = 0; h < 2; ++h) {
                    const int c0 = 8 * g + 4 * h, d = dv[h];
#pragma unroll
                    for (int j = 0; j < 4; ++j) {
                        const int k = c0 + j;
                        float alt = d ? ((j < 3) ? lx[4 * h + j + 1] : 0.f) : lx[4 * h + j];  // src[k]
                        float agt = d ? lx[4 * h + j] : ((j > 0) ? lx[4 * h + j - 1] : 0.f);  // src[k-1]
                        float fv = (k < i) ? alt : ((k == i) ? 0.f : agt);
                        as += fabsf(fv); qs += fv * fv; rs += fmaxf(fv, 0.f);
                        o[4 * h + j] = bfbits(fv);
                    }
                }
                dst[g] = *(uint4*)o;
            }
            rs = wave_red(rs); as = wave_red(as); qs = wave_red(qs);
            if (lane == 0) { rsS[i] = rs; pAbsS[i] = as; pSqS[i] = qs; }
        }
    } else if (b < 2560) {
        // ---- prep: 64x64 transpose tiles; cur/pre -> bf16 (+T) ----
        const int bb = b - 2048;
        const int x = bb & 63, y = (bb >> 6) & 3, z = bb >> 8;
        const int i0 = x * 64, d0 = y * 64;
        const float* src = z ? pre : cur;
        __bf16* dstT = z ? preT : curT;
        const int r = t >> 2, c4 = (t & 3) * 16;
        const float* srow = src + (size_t)(i0 + r) * DD + d0 + c4;
        alignas(16) unsigned short loc[16];
#pragma unroll
        for (int e = 0; e < 4; ++e) {
            float4 v = ((const float4*)srow)[e];
            loc[e * 4 + 0] = bfbits(v.x);
            loc[e * 4 + 1] = bfbits(v.y);
            loc[e * 4 + 2] = bfbits(v.z);
            loc[e * 4 + 3] = bfbits(v.w);
        }
#pragma unroll
        for (int e = 0; e < 16; ++e) tile[r][c4 + e] = loc[e];
        if (z == 0) {
            __bf16* drow = cur_bf + (size_t)(i0 + r) * DD + d0 + c4;
            *(uint4*)drow = *(uint4*)&loc[0];
            *(uint4*)(drow + 8) = *(uint4*)&loc[8];
        }
        __syncthreads();
        alignas(16) unsigned short o[16];
#pragma unroll
        for (int e = 0; e < 16; ++e) o[e] = tile[c4 + e][r];
        __bf16* trow = dstT + (size_t)(d0 + r) * NN + i0 + c4;
        *(uint4*)trow = *(uint4*)&o[0];
        *(uint4*)(trow + 8) = *(uint4*)&o[8];
    } else {
        // ---- proj matrices -> bf16 (transposed for id<5) ----
        const int bb = b - 2560;
        const int id = bb >> 8, r = bb & 255;
        const float* src = id == 0 ? r_proj_s : id == 1 ? r_proj_t : id == 2 ? node_pj
                         : id == 3 ? spa_pj : id == 4 ? tmp_pj : theta_w;
        __bf16* dst = id == 0 ? pTs : id == 1 ? pTt : id == 2 ? pTn
                    : id == 3 ? pTspa : id == 4 ? pTtmp : thetaBf;
        float v = src[r * DD + t];
        if (id < 5) dst[t * DD + r] = (__bf16)v;
        else        dst[r * DD + t] = (__bf16)v;
    }
}

// ---------------- big dual GEMM, K-split across waves (round-3 structure, validated) ----------------
__global__ __launch_bounds__(256, 2) void k_big(const __bf16* __restrict__ Mt, const __bf16* __restrict__ Ms,
                                                const __bf16* __restrict__ preT, const __bf16* __restrict__ curT,
                                                const float* __restrict__ negMt, const float* __restrict__ negMs,
                                                const float* __restrict__ cur,
                                                const float* __restrict__ rsT, const float* __restrict__ rsS,
                                                __bf16* __restrict__ embT, __bf16* __restrict__ embS,
                                                float* __restrict__ pDiff) {
    const int flat = blockIdx.x + 4 * (blockIdx.y + 64 * blockIdx.z);
    const int swz = (flat & 7) * 64 + (flat >> 3);
    const int bx = swz & 3, by = (swz >> 2) & 63, z = swz >> 8;
    const __bf16* A  = z ? Ms : Mt;
    const __bf16* BT = z ? curT : preT;
    const float* negM = z ? negMs : negMt;
    const float* rs   = z ? rsS : rsT;
    __bf16* emb       = z ? embS : embT;
    const int n0 = bx * 64, m0 = by * 64;
    __shared__ __align__(16) char smraw[65536];
    __bf16 (*sm)[2][64][64] = (__bf16 (*)[2][64][64])smraw;   // [buf][A/B][row][col]
    float* scr = (float*)smraw;                               // reduce scratch (overlays bufs 0,1)
    f32x16 accR[2][2], accL[2][2];
#pragma unroll
    for (int i = 0; i < 2; ++i)
#pragma unroll
        for (int j = 0; j < 2; ++j) { accR[i][j] = (f32x16)0.f; accL[i][j] = (f32x16)0.f; }
    const int t = threadIdx.x, w = t >> 6, lane = t & 63;
    const int lr = lane >> 3, lc = lane & 7;
    const int q0 = 2 * w, q1 = q0 + 1;
    const int csw = (lc ^ lr) * 8;
    const __bf16* gA0 = A + (size_t)(m0 + 8 * q0 + lr) * NN + csw;
    const __bf16* gA1 = A + (size_t)(m0 + 8 * q1 + lr) * NN + csw;
    const __bf16* gB0 = BT + (size_t)(n0 + 8 * q0 + lr) * NN + csw;
    const __bf16* gB1 = BT + (size_t)(n0 + 8 * q1 + lr) * NN + csw;
    auto stage = [&](int b, int tk) {
        const int ko = tk * 64;
        GLD16(gA0 + ko, &sm[b][0][8 * q0][0]);
        GLD16(gA1 + ko, &sm[b][0][8 * q1][0]);
        GLD16(gB0 + ko, &sm[b][1][8 * q0][0]);
        GLD16(gB1 + ko, &sm[b][1][8 * q1][0]);
    };
    stage(0, 0); stage(1, 1); stage(2, 2); stage(3, 3);
    asm volatile("s_waitcnt vmcnt(8)" ::: "memory");          // tiles 0,1 landed
    __builtin_amdgcn_s_barrier();
    __builtin_amdgcn_sched_barrier(0);
    const int fr = lane & 31, h = lane >> 5;
    const int swc = ((2 * w + h) ^ (fr & 7)) * 8;             // swizzled 16B chunk (constant)
    for (int it = 0; it < 32; ++it) {
        const int b0 = (2 * it) & 3, b1 = b0 + 1;
        bf16x8 a[2][2], bb[2][2];
#pragma unroll
        for (int mi = 0; mi < 2; ++mi) {
            a[0][mi]  = *(const bf16x8*)&sm[b0][0][mi * 32 + fr][swc];
            a[1][mi]  = *(const bf16x8*)&sm[b1][0][mi * 32 + fr][swc];
            bb[0][mi] = *(const bf16x8*)&sm[b0][1][mi * 32 + fr][swc];
            bb[1][mi] = *(const bf16x8*)&sm[b1][1][mi * 32 + fr][swc];
        }
        asm volatile("s_waitcnt lgkmcnt(0)" ::: "memory");    // fragments in regs
        __builtin_amdgcn_sched_barrier(0);
        __builtin_amdgcn_s_barrier();                         // bufs b0,b1 free
        __builtin_amdgcn_sched_barrier(0);
        if (it < 30) { stage(b0, 2 * it + 4); stage(b1, 2 * it + 5); }
        __builtin_amdgcn_sched_barrier(0);
        __builtin_amdgcn_s_setprio(1);
#pragma unroll
        for (int u = 0; u < 2; ++u)
#pragma unroll
            for (int mi = 0; mi < 2; ++mi) {
                bf16x8 ar = brelu(a[u][mi]);
#pragma unroll
                for (int ni = 0; ni < 2; ++ni) {
                    accR[mi][ni] = MFMA32(a[u][mi], bb[u][ni], accR[mi][ni]);
                    accL[mi][ni] = MFMA32(ar,       bb[u][ni], accL[mi][ni]);
                }
            }
        __builtin_amdgcn_s_setprio(0);
        if (it < 31) {
            if (it < 30) asm volatile("s_waitcnt vmcnt(8)" ::: "memory");   // next pair landed
            else         asm volatile("s_waitcnt vmcnt(0)" ::: "memory");
            __builtin_amdgcn_s_barrier();
            __builtin_amdgcn_sched_barrier(0);
        }
    }
    // cross-wave reduce: wave w owns quadrant (w>>1, w&1)
    f32x16 oR, oL;
    if      (w == 0) red_owner<0>(accR, accL, scr, lane, oR, oL);
    else if (w == 1) red_owner<1>(accR, accL, scr, lane, oR, oL);
    else if (w == 2) red_owner<2>(accR, accL, scr, lane, oR, oL);
    else             red_owner<3>(accR, accL, scr, lane, oR, oL);
    const int mi = w >> 1, ni = w & 1;
    float sumd = 0.f;
#pragma unroll
    for (int reg = 0; reg < 16; ++reg) {
        const int rr = (reg & 3) + 8 * (reg >> 2) + 4 * h;
        const int gr = m0 + mi * 32 + rr;
        const int gc = n0 + ni * 32 + fr;
        const size_t idx = (size_t)gr * DD + gc;
        float diff = oR[reg] + negM[idx];                     // recon - master
        sumd += diff * diff;
        emb[idx] = (__bf16)((oL[reg] + cur[idx]) * (1.f / (rs[gr] + 1.f)));
    }
    sumd = wave_red(sumd);
    float* sredp = (float*)(smraw + 32768);                   // bufs 2,3 region (free)
    if (lane == 0) sredp[w] = sumd;
    __syncthreads();
    if (t == 0)
        pDiff[z * 256 + by * 4 + bx] = sredp[0] + sredp[1] + sredp[2] + sredp[3];
}

// ---------------- shared MFMA inner step for the small (padded-LDS) GEMMs ----------------
__device__ inline void mfma_step_s(const __bf16 (&As)[64][72], const __bf16 (&Bs)[64][72],
                                   int wr, int wc, int quad, int l16,
                                   f32x4 (&accR)[2][2]) {
#pragma unroll
    for (int ks = 0; ks < 2; ++ks) {
        const int kc = ks * 32 + quad * 8;
        bf16x8 a0 = *(const bf16x8*)&As[wr * 32 + l16][kc];
        bf16x8 a1 = *(const bf16x8*)&As[wr * 32 + 16 + l16][kc];
        bf16x8 b0 = *(const bf16x8*)&Bs[wc * 32 + l16][kc];
        bf16x8 b1 = *(const bf16x8*)&Bs[wc * 32 + 16 + l16][kc];
        accR[0][0] = MFMA16(a0, b0, accR[0][0]);
        accR[0][1] = MFMA16(a0, b1, accR[0][1]);
        accR[1][0] = MFMA16(a1, b0, accR[1][0]);
        accR[1][1] = MFMA16(a1, b1, accR[1][1]);
    }
}

// ---------------- small GEMMs: -master_s, -master_t, node_fea ----------------
__global__ __launch_bounds__(256) void k_small3(const __bf16* __restrict__ cur_bf,
                                                const __bf16* __restrict__ pTs, const __bf16* __restrict__ pTt,
                                                const __bf16* __restrict__ pTn,
                                                float* __restrict__ negMs, float* __restrict__ negMt,
                                                float* __restrict__ nodeFea) {
    const int z = blockIdx.z;
    const __bf16* BT = z == 0 ? pTs : (z == 1 ? pTt : pTn);
    const int n0 = blockIdx.x * 64, m0 = blockIdx.y * 64;
    __shared__ __bf16 As[64][72], Bs[64][72];
    f32x4 accR[2][2];
#pragma unroll
    for (int i = 0; i < 2; ++i)
#pragma unroll
        for (int j = 0; j < 2; ++j) accR[i][j] = (f32x4)0.f;
    const int t = threadIdx.x, w = t >> 6, lane = t & 63, quad = lane >> 4, l16 = lane & 15;
    const int wr = w >> 1, wc = w & 1;
    const int sr = t >> 2, sc = (t & 3) * 16;
    const __bf16* gA = cur_bf + (size_t)(m0 + sr) * DD + sc;
    const __bf16* gB = BT + (size_t)(n0 + sr) * DD + sc;
    for (int kt = 0; kt < DD / 64; ++kt) {
        uint4 av0 = *(const uint4*)(gA);
        uint4 av1 = *(const uint4*)(gA + 8);
        uint4 bv0 = *(const uint4*)(gB);
        uint4 bv1 = *(const uint4*)(gB + 8);
        __syncthreads();
        *(uint4*)&As[sr][sc] = av0; *(uint4*)&As[sr][sc + 8] = av1;
        *(uint4*)&Bs[sr][sc] = bv0; *(uint4*)&Bs[sr][sc + 8] = bv1;
        __syncthreads();
        mfma_step_s(As, Bs, wr, wc, quad, l16, accR);
        gA += 64; gB += 64;
    }
#pragma unroll
    for (int mi = 0; mi < 2; ++mi)
#pragma unroll
        for (int ni = 0; ni < 2; ++ni)
#pragma unroll
            for (int r = 0; r < 4; ++r) {
                int gr = m0 + wr * 32 + mi * 16 + quad * 4 + r;
                int gc = n0 + wc * 32 + ni * 16 + l16;
                size_t idx = (size_t)gr * DD + gc;
                float v = accR[mi][ni][r];
                if (z == 0) negMs[idx] = -v;
                else if (z == 1) negMt[idx] = -v;
                else nodeFea[idx] = v;
            }
}

// ---------------- edge-feature projections + fused attention partial dots ----------------
__global__ __launch_bounds__(256) void k_fea(const __bf16* __restrict__ embS, const __bf16* __restrict__ embT,
                                             const __bf16* __restrict__ pTspa, const __bf16* __restrict__ pTtmp,
                                             const float* __restrict__ nodeF,
                                             float* __restrict__ spaF, float* __restrict__ tmpF,
                                             float* __restrict__ pSpa, float* __restrict__ pTmp) {
    const int z = blockIdx.z;
    const __bf16* Ae = z ? embT : embS;
    const __bf16* BT = z ? pTtmp : pTspa;
    float* outF = z ? tmpF : spaF;
    float* pOut = z ? pTmp : pSpa;
    const int n0 = blockIdx.x * 64, m0 = blockIdx.y * 64;
    __shared__ __bf16 As[64][72], Bs[64][72];
    f32x4 accR[2][2];
#pragma unroll
    for (int i = 0; i < 2; ++i)
#pragma unroll
        for (int j = 0; j < 2; ++j) accR[i][j] = (f32x4)0.f;
    const int t = threadIdx.x, w = t >> 6, lane = t & 63, quad = lane >> 4, l16 = lane & 15;
    const int wr = w >> 1, wc = w & 1;
    const int sr = t >> 2, sc = (t & 3) * 16;
    const __bf16* gA = Ae + (size_t)(m0 + sr) * DD + sc;
    const __bf16* gB = BT + (size_t)(n0 + sr) * DD + sc;
    for (int kt = 0; kt < DD / 64; ++kt) {
        uint4 av0 = *(const uint4*)(gA);
        uint4 av1 = *(const uint4*)(gA + 8);
        uint4 bv0 = *(const uint4*)(gB);
        uint4 bv1 = *(const uint4*)(gB + 8);
        __syncthreads();
        *(uint4*)&As[sr][sc] = av0; *(uint4*)&As[sr][sc + 8] = av1;
        *(uint4*)&Bs[sr][sc] = bv0; *(uint4*)&Bs[sr][sc + 8] = bv1;
        __syncthreads();
        mfma_step_s(As, Bs, wr, wc, quad, l16, accR);
        gA += 64; gB += 64;
    }
    const int slice = blockIdx.x * 2 + wc;
#pragma unroll
    for (int mi = 0; mi < 2; ++mi)
#pragma unroll
        for (int r = 0; r < 4; ++r) {
            const int gr = m0 + wr * 32 + mi * 16 + quad * 4 + r;
            float s = 0.f;
#pragma unroll
            for (int ni = 0; ni < 2; ++ni) {
                const int gc = n0 + wc * 32 + ni * 16 + l16;
                const size_t idx = (size_t)gr * DD + gc;
                const float v = accR[mi][ni][r];
                outF[idx] = v;
                s += v * nodeF[idx];
            }
            s += __shfl_xor(s, 1, 64);
            s += __shfl_xor(s, 2, 64);
            s += __shfl_xor(s, 4, 64);
            s += __shfl_xor(s, 8, 64);
            if (l16 == 0) pOut[(size_t)slice * NN + gr] = s;
        }
}

// ---------------- final: val @ theta_w^T + b, relu -> d_out (+ fused loss in block 0) ----------------
__global__ __launch_bounds__(256) void k_final(const float* __restrict__ spaF, const float* __restrict__ tmpF,
                                               const float* __restrict__ pSpa, const float* __restrict__ pTmp,
                                               const __bf16* __restrict__ thetaBf, const float* __restrict__ thetaB,
                                               const float* __restrict__ pAbsT, const float* __restrict__ pSqT,
                                               const float* __restrict__ pAbsS, const float* __restrict__ pSqS,
                                               const float* __restrict__ pDiff,
                                               float* __restrict__ out) {
    const int n0 = blockIdx.x * 64, m0 = blockIdx.y * 64;
    __shared__ __bf16 As[64][72], Bs[64][72];
    f32x4 accR[2][2];
#pragma unroll
    for (int i = 0; i < 2; ++i)
#pragma unroll
        for (int j = 0; j < 2; ++j) accR[i][j] = (f32x4)0.f;
    const int t = threadIdx.x, w = t >> 6, lane = t & 63, quad = lane >> 4, l16 = lane & 15;
    const int wr = w >> 1, wc = w & 1;
    const int sr = t >> 2, sc = (t & 3) * 16;
    const int row = m0 + sr;
    float sa = 0.f, ta = 0.f;
#pragma unroll
    for (int j = 0; j < 8; ++j) {
        sa += pSpa[(size_t)j * NN + row];
        ta += pTmp[(size_t)j * NN + row];
    }
    sa *= 0.0625f; ta *= 0.0625f;   // 1/sqrt(256)
    const float* gS = spaF + (size_t)row * DD + sc;
    const float* gT = tmpF + (size_t)row * DD + sc;
    const __bf16* gB = thetaBf + (size_t)(n0 + sr) * DD + sc;
    for (int kt = 0; kt < DD / 64; ++kt) {
        __bf16 tmp[16];
#pragma unroll
        for (int e4 = 0; e4 < 4; ++e4) {
            float4 vs = ((const float4*)gS)[e4];
            float4 vt = ((const float4*)gT)[e4];
            tmp[e4 * 4 + 0] = (__bf16)(sa * vs.x + ta * vt.x);
            tmp[e4 * 4 + 1] = (__bf16)(sa * vs.y + ta * vt.y);
            tmp[e4 * 4 + 2] = (__bf16)(sa * vs.z + ta * vt.z);
            tmp[e4 * 4 + 3] = (__bf16)(sa * vs.w + ta * vt.w);
        }
        uint4 bv0 = *(const uint4*)(gB);
        uint4 bv1 = *(const uint4*)(gB + 8);
        __syncthreads();
        *(uint4*)&As[sr][sc] = *(uint4*)&tmp[0]; *(uint4*)&As[sr][sc + 8] = *(uint4*)&tmp[8];
        *(uint4*)&Bs[sr][sc] = bv0; *(uint4*)&Bs[sr][sc + 8] = bv1;
        __syncthreads();
        mfma_step_s(As, Bs, wr, wc, quad, l16, accR);
        gS += 64; gT += 64; gB += 64;
    }
#pragma unroll
    for (int mi = 0; mi < 2; ++mi)
#pragma unroll
        for (int ni = 0; ni < 2; ++ni)
#pragma unroll
            for (int r = 0; r < 4; ++r) {
                int gr = m0 + wr * 32 + mi * 16 + quad * 4 + r;
                int gc = n0 + wc * 32 + ni * 16 + l16;
                float v = accR[mi][ni][r] + thetaB[gc];
                out[(size_t)gr * DD + gc] = fmaxf(v, 0.f);
            }
    // ---- fused loss (one block) ----
    if (blockIdx.x == 0 && blockIdx.y == 0) {
        float aT = 0.f, qT = 0.f, aS = 0.f, qS = 0.f;
#pragma unroll
        for (int j = 0; j < 16; ++j) {
            const int i = t + 256 * j;
            aT += pAbsT[i]; qT += pSqT[i]; aS += pAbsS[i]; qS += pSqS[i];
        }
        float dT = pDiff[t], dS = pDiff[256 + t];
        aT = wave_red(aT); qT = wave_red(qT); aS = wave_red(aS); qS = wave_red(qS);
        dT = wave_red(dT); dS = wave_red(dS);
        float (*red)[4] = (float (*)[4])As;
        if (lane == 0) { red[0][w] = aT; red[1][w] = qT; red[2][w] = aS; red[3][w] = qS; red[4][w] = dT; red[5][w] = dS; }
        __syncthreads();
        if (t == 0) {
            float s[6];
#pragma unroll
            for (int k = 0; k < 6; ++k) s[k] = red[k][0] + red[k][1] + red[k][2] + red[k][3];
            float l = s[0] + 0.001f * sqrtf(s[1]) + 0.2f * sqrtf(s[4])    // temporal
                    + s[2] + 0.001f * sqrtf(s[3]) + 0.2f * sqrtf(s[5]);   // spatial
            out[(size_t)NN * DD] = l;
        }
    }
}

extern "C" void kernel_launch(void* const* d_in, const int* in_sizes, int n_in,
                              void* d_out, int out_size, void* d_ws, size_t ws_size,
                              hipStream_t stream) {
    (void)in_sizes; (void)n_in; (void)out_size; (void)ws_size;
    const float* cur      = (const float*)d_in[0];
    const float* pre      = (const float*)d_in[1];
    const float* r_proj_s = (const float*)d_in[2];
    const float* inc_s    = (const float*)d_in[3];
    const float* r_proj_t = (const float*)d_in[4];
    const float* inc_t    = (const float*)d_in[5];
    const float* node_pj  = (const float*)d_in[6];
    const float* spa_pj   = (const float*)d_in[7];
    const float* tmp_pj   = (const float*)d_in[8];
    const float* theta_w  = (const float*)d_in[9];
    const float* theta_b  = (const float*)d_in[10];
    float* out = (float*)d_out;

    char* p = (char*)d_ws;
    auto alloc = [&](size_t bytes) -> void* {
        void* r = (void*)p;
        p += (bytes + 255) & ~(size_t)255;
        return r;
    };
    __bf16* Mt      = (__bf16*)alloc((size_t)NN * NN * 2);
    __bf16* Ms      = (__bf16*)alloc((size_t)NN * NN * 2);
    __bf16* cur_bf  = (__bf16*)alloc((size_t)NN * DD * 2);
    __bf16* curT    = (__bf16*)alloc((size_t)NN * DD * 2);
    __bf16* preT    = (__bf16*)alloc((size_t)NN * DD * 2);
    __bf16* pTs     = (__bf16*)alloc((size_t)DD * DD * 2);
    __bf16* pTt     = (__bf16*)alloc((size_t)DD * DD * 2);
    __bf16* pTn     = (__bf16*)alloc((size_t)DD * DD * 2);
    __bf16* pTspa   = (__bf16*)alloc((size_t)DD * DD * 2);
    __bf16* pTtmp   = (__bf16*)alloc((size_t)DD * DD * 2);
    __bf16* thetaBf = (__bf16*)alloc((size_t)DD * DD * 2);
    __bf16* embS    = (__bf16*)alloc((size_t)NN * DD * 2);
    __bf16* embT    = (__bf16*)alloc((size_t)NN * DD * 2);
    float* negMs    = (float*)alloc((size_t)NN * DD * 4);
    float* negMt    = (float*)alloc((size_t)NN * DD * 4);
    float* nodeFea  = (float*)alloc((size_t)NN * DD * 4);
    float* spaF     = (float*)alloc((size_t)NN * DD * 4);
    float* tmpF     = (float*)alloc((size_t)NN * DD * 4);
    float* rsS      = (float*)alloc((size_t)NN * 4);
    float* rsT      = (float*)alloc((size_t)NN * 4);
    float* pSpa     = (float*)alloc((size_t)8 * NN * 4);
    float* pTmp     = (float*)alloc((size_t)8 * NN * 4);
    float* pAbsT    = (float*)alloc((size_t)NN * 4);
    float* pSqT     = (float*)alloc((size_t)NN * 4);
    float* pAbsS    = (float*)alloc((size_t)NN * 4);
    float* pSqS     = (float*)alloc((size_t)NN * 4);
    float* pDiff    = (float*)alloc(512 * 4);

    k_prec<<<4096, 256, 0, stream>>>(cur, pre, r_proj_s, r_proj_t, node_pj, spa_pj, tmp_pj, theta_w,
                                     inc_t, inc_s,
                                     cur_bf, curT, preT, pTs, pTt, pTn, pTspa, pTtmp, thetaBf,
                                     Mt, Ms, rsT, pAbsT, pSqT, rsS, pAbsS, pSqS);
    k_small3<<<dim3(4, 64, 3), 256, 0, stream>>>(cur_bf, pTs, pTt, pTn, negMs, negMt, nodeFea);
    k_big<<<dim3(4, 64, 2), 256, 0, stream>>>(Mt, Ms, preT, curT, negMt, negMs, cur,
                                              rsT, rsS, embT, embS, pDiff);
    k_fea<<<dim3(4, 64, 2), 256, 0, stream>>>(embS, embT, pTspa, pTtmp, nodeFea,
                                              spaF, tmpF, pSpa, pTmp);
    k_final<<<dim3(4, 64), 256, 0, stream>>>(spaF, tmpF, pSpa, pTmp, thetaBf, theta_b,
                                             pAbsT, pSqT, pAbsS, pSqS, pDiff, out);
}